// Round 2
// baseline (324.350 us; speedup 1.0000x reference)
//
#include <hip/hip_runtime.h>

#define L 2048
#define HSZ 1024
#define HEADS 16
#define HDIM 64
#define NBATCH 2
#define M (NBATCH * L)        // 4096 rows

typedef float f32x4 __attribute__((ext_vector_type(4)));
typedef short short8v __attribute__((ext_vector_type(8)));

__device__ __forceinline__ unsigned short f2bf(float f) {
    unsigned int u = __builtin_bit_cast(unsigned int, f);
    u += 0x7FFFu + ((u >> 16) & 1u);   // RNE
    return (unsigned short)(u >> 16);
}

__device__ __forceinline__ unsigned int cvt_pk_bf16(float lo, float hi) {
    unsigned int r;
    asm("v_cvt_pk_bf16_f32 %0, %1, %2" : "=v"(r) : "v"(lo), "v"(hi));
    return r;
}

// ---------------------------------------------------------------------------
// Transpose + convert weights: Wt[n][k] = bf16(W[k][n]), 1024x1024, z picks W.
// ---------------------------------------------------------------------------
__global__ __launch_bounds__(256) void wtrans_kernel(
    const float* __restrict__ W0, const float* __restrict__ W1,
    const float* __restrict__ W2, const float* __restrict__ W3,
    unsigned short* __restrict__ T0, unsigned short* __restrict__ T1,
    unsigned short* __restrict__ T2, unsigned short* __restrict__ T3)
{
    const float* W; unsigned short* T;
    int z = blockIdx.z;
    if (z == 0) { W = W0; T = T0; }
    else if (z == 1) { W = W1; T = T1; }
    else if (z == 2) { W = W2; T = T2; }
    else { W = W3; T = T3; }

    __shared__ __align__(16) unsigned short tl[64][72];
    int t = threadIdx.x;
    int k0 = blockIdx.y * 64, n0 = blockIdx.x * 64;

    int kl = t >> 2, nc = (t & 3) * 16;
    const float* src = W + (size_t)(k0 + kl) * HSZ + n0 + nc;
#pragma unroll
    for (int q = 0; q < 4; q++) {
        float4 v = ((const float4*)src)[q];
        tl[kl][nc + q * 4 + 0] = f2bf(v.x);
        tl[kl][nc + q * 4 + 1] = f2bf(v.y);
        tl[kl][nc + q * 4 + 2] = f2bf(v.z);
        tl[kl][nc + q * 4 + 3] = f2bf(v.w);
    }
    __syncthreads();
    int nl = t >> 2, kc = (t & 3) * 16;
    unsigned short tmp[16];
#pragma unroll
    for (int e = 0; e < 16; e++) tmp[e] = tl[kc + e][nl];
    unsigned short* dst = T + (size_t)(n0 + nl) * HSZ + k0 + kc;
    ((uint4*)dst)[0] = *(uint4*)&tmp[0];
    ((uint4*)dst)[1] = *(uint4*)&tmp[8];
}

// ---------------------------------------------------------------------------
// Transpose V head-panels: Vb flat panels [p][2048][64] -> Vt [p][64][2048].
// ---------------------------------------------------------------------------
__global__ __launch_bounds__(256) void vtrans_kernel(
    const unsigned short* __restrict__ Vb, unsigned short* __restrict__ Vt)
{
    int p = blockIdx.y;
    int j0 = blockIdx.x * 64;
    const unsigned short* Vp = Vb + (size_t)p * L * HDIM;
    unsigned short* Tp = Vt + (size_t)p * HDIM * L;
    __shared__ __align__(16) unsigned short tl[64][72];
    int t = threadIdx.x;
    int jl = t >> 2, c0 = (t & 3) * 16;
    const unsigned short* src = Vp + (size_t)(j0 + jl) * HDIM + c0;
    *(uint4*)&tl[jl][c0]     = ((const uint4*)src)[0];
    *(uint4*)&tl[jl][c0 + 8] = ((const uint4*)src)[1];
    __syncthreads();
    int cl = t >> 2, jc = (t & 3) * 16;
    unsigned short tmp[16];
#pragma unroll
    for (int e = 0; e < 16; e++) tmp[e] = tl[jc + e][cl];
    unsigned short* dst = Tp + (size_t)cl * L + j0 + jc;
    ((uint4*)dst)[0] = *(uint4*)&tmp[0];
    ((uint4*)dst)[1] = *(uint4*)&tmp[8];
}

// ---------------------------------------------------------------------------
// GEMM: out[M][1024] = A[M][1024] @ Bt[1024][1024]^T + bias, then *scale.
// ---------------------------------------------------------------------------
template<bool ABF16, bool OUTBF16>
__global__ __launch_bounds__(256) void gemm_bt_kernel(
    const void* __restrict__ Aptr, const unsigned short* __restrict__ Bt,
    const float* __restrict__ bias, float scale, void* __restrict__ outp)
{
    __shared__ __align__(16) unsigned short As[128][40];
    __shared__ __align__(16) unsigned short Bs[128][40];

    int t = threadIdx.x;
    int lane = t & 63, w = t >> 6;
    int lr = lane & 15, lg = lane >> 4;
    int mb = blockIdx.y * 128, nb = blockIdx.x * 128;
    int wm = (w >> 1) * 64, wn = (w & 1) * 64;
    int r = t >> 1, cc = (t & 1) * 16;

    f32x4 acc[4][4] = {};

    for (int kt = 0; kt < HSZ; kt += 32) {
        if (ABF16) {
            const unsigned short* A = (const unsigned short*)Aptr + (size_t)(mb + r) * HSZ + kt + cc;
            *(uint4*)&As[r][cc]     = ((const uint4*)A)[0];
            *(uint4*)&As[r][cc + 8] = ((const uint4*)A)[1];
        } else {
            const float* A = (const float*)Aptr + (size_t)(mb + r) * HSZ + kt + cc;
            unsigned short tmp[16];
#pragma unroll
            for (int q = 0; q < 4; q++) {
                float4 v = ((const float4*)A)[q];
                tmp[q * 4 + 0] = f2bf(v.x); tmp[q * 4 + 1] = f2bf(v.y);
                tmp[q * 4 + 2] = f2bf(v.z); tmp[q * 4 + 3] = f2bf(v.w);
            }
            *(uint4*)&As[r][cc]     = *(uint4*)&tmp[0];
            *(uint4*)&As[r][cc + 8] = *(uint4*)&tmp[8];
        }
        {
            const unsigned short* B = Bt + (size_t)(nb + r) * HSZ + kt + cc;
            *(uint4*)&Bs[r][cc]     = ((const uint4*)B)[0];
            *(uint4*)&Bs[r][cc + 8] = ((const uint4*)B)[1];
        }
        __syncthreads();

        short8v af[4], bf[4];
#pragma unroll
        for (int s = 0; s < 4; s++) af[s] = *(const short8v*)&As[wm + s * 16 + lr][8 * lg];
#pragma unroll
        for (int s = 0; s < 4; s++) bf[s] = *(const short8v*)&Bs[wn + s * 16 + lr][8 * lg];
#pragma unroll
        for (int i = 0; i < 4; i++)
#pragma unroll
            for (int j = 0; j < 4; j++)
                acc[i][j] = __builtin_amdgcn_mfma_f32_16x16x32_bf16(af[i], bf[j], acc[i][j], 0, 0, 0);
        __syncthreads();
    }

#pragma unroll
    for (int j = 0; j < 4; j++) {
        int col = nb + wn + j * 16 + lr;
        float bv = bias[col];
#pragma unroll
        for (int i = 0; i < 4; i++) {
            int row0 = mb + wm + i * 16 + lg * 4;
#pragma unroll
            for (int rg = 0; rg < 4; rg++) {
                float v = (acc[i][j][rg] + bv) * scale;
                if (OUTBF16)
                    ((unsigned short*)outp)[(size_t)(row0 + rg) * HSZ + col] = f2bf(v);
                else
                    ((float*)outp)[(size_t)(row0 + rg) * HSZ + col] = v;
            }
        }
    }
}

// ---------------------------------------------------------------------------
// Phase 1: rcpC[head][j] = 1 / sum_{i>=j} exp(S_ij).  S^T = mfma(K, Q).
// ---------------------------------------------------------------------------
__global__ __launch_bounds__(256) void colsum_kernel(
    const unsigned short* __restrict__ Qb, const unsigned short* __restrict__ Kb,
    float* __restrict__ rcpC)
{
    int head = blockIdx.y;
    int jb = blockIdx.x * 64;
    const unsigned short* Qh = Qb + (size_t)head * L * HDIM;
    const unsigned short* Kh = Kb + (size_t)head * L * HDIM;
    int t = threadIdx.x, lane = t & 63, w = t >> 6;
    int lr = lane & 15, lg = lane >> 4;

    short8v af[4][2];
#pragma unroll
    for (int sj = 0; sj < 4; sj++)
#pragma unroll
        for (int kk = 0; kk < 2; kk++)
            af[sj][kk] = *(const short8v*)&Kh[(size_t)(jb + sj * 16 + lr) * HDIM + kk * 32 + 8 * lg];

    float accs[4][4] = {};

    for (int it = jb + w * 16; it < L; it += 64) {
        short8v bf[2];
#pragma unroll
        for (int kk = 0; kk < 2; kk++)
            bf[kk] = *(const short8v*)&Qh[(size_t)(it + lr) * HDIM + kk * 32 + 8 * lg];
        int i = it + lr;
#pragma unroll
        for (int sj = 0; sj < 4; sj++) {
            f32x4 d = {0.0f, 0.0f, 0.0f, 0.0f};
            d = __builtin_amdgcn_mfma_f32_16x16x32_bf16(af[sj][0], bf[0], d, 0, 0, 0);
            d = __builtin_amdgcn_mfma_f32_16x16x32_bf16(af[sj][1], bf[1], d, 0, 0, 0);
#pragma unroll
            for (int rg = 0; rg < 4; rg++) {
                int j = jb + sj * 16 + lg * 4 + rg;
                if (i >= j) accs[sj][rg] += __expf(d[rg]);
            }
        }
    }

    __shared__ float part[4][64];
#pragma unroll
    for (int sj = 0; sj < 4; sj++)
#pragma unroll
        for (int rg = 0; rg < 4; rg++) {
            float v = accs[sj][rg];
            v += __shfl_xor(v, 1); v += __shfl_xor(v, 2);
            v += __shfl_xor(v, 4); v += __shfl_xor(v, 8);
            if (lr == 0) part[w][sj * 16 + lg * 4 + rg] = v;
        }
    __syncthreads();
    if (t < 64) {
        float s = part[0][t] + part[1][t] + part[2][t] + part[3][t];
        rcpC[(size_t)head * L + jb + t] = 1.0f / s;
    }
}

// ---------------------------------------------------------------------------
// Phase 2 (zero-LDS, zero-barrier): one wave per 32 q-rows.
// S^T = mfma(K,Q): lane holds P^T(j=lg*4+rg, i=lr).  P -> bf16 via cvt_pk,
// PV B-fragment assembled with 8 bpermutes/isub, ctx^T = mfma(V^T, P^T).
// ---------------------------------------------------------------------------
__global__ __launch_bounds__(64) void attn_kernel(
    const unsigned short* __restrict__ Qb, const unsigned short* __restrict__ Kb,
    const unsigned short* __restrict__ Vt, const float* __restrict__ rcpC,
    unsigned short* __restrict__ Ctx)
{
    int head = blockIdx.y;
    int tile = blockIdx.x;          // 32 q-rows per tile
    int iw = tile * 32;
    const unsigned short* Qh = Qb + (size_t)head * L * HDIM;
    const unsigned short* Kh = Kb + (size_t)head * L * HDIM;
    const unsigned short* Vh = Vt + (size_t)head * HDIM * L;   // [64][2048]
    const float* rc = rcpC + (size_t)head * L;
    unsigned short* Ch = Ctx + (size_t)head * L * HDIM;

    int lane = threadIdx.x;
    int lr = lane & 15, lg = lane >> 4;
    int src0 = ((lane & 16) << 1) + lr;   // ((lg&1)*2)*16 + lr
    int src1 = src0 + 16;
    bool jlow = (lg < 2);

    // Q as B-fragment: lane holds Q[i = iw+isub*16+lr][d = kd*32+8*lg+e]
    short8v bq[2][2];
#pragma unroll
    for (int isub = 0; isub < 2; isub++)
#pragma unroll
        for (int kd = 0; kd < 2; kd++)
            bq[isub][kd] = *(const short8v*)&Qh[(size_t)(iw + isub * 16 + lr) * HDIM + kd * 32 + 8 * lg];

    f32x4 acc[4][2] = {};   // ctx^T [csub][isub]: D(c = lg*4+rg, i = lr)

    for (int wnd = 0; wnd <= tile; wnd++) {
        int jt = wnd * 32;
        // K as A-fragment: lane holds K[j = jt+jsub*16+lr][d]
        short8v ak[2][2];
#pragma unroll
        for (int jsub = 0; jsub < 2; jsub++)
#pragma unroll
            for (int kd = 0; kd < 2; kd++)
                ak[jsub][kd] = *(const short8v*)&Kh[(size_t)(jt + jsub * 16 + lr) * HDIM + kd * 32 + 8 * lg];
        // V^T as A-fragment: lane holds V^T[c = csub*16+lr][j = jt+8*lg+e]
        short8v av[4];
#pragma unroll
        for (int csub = 0; csub < 4; csub++)
            av[csub] = *(const short8v*)&Vh[(size_t)(csub * 16 + lr) * L + jt + 8 * lg];

        f32x4 rcv[2];
#pragma unroll
        for (int jsub = 0; jsub < 2; jsub++)
            rcv[jsub] = *(const f32x4*)&rc[jt + jsub * 16 + lg * 4];

        unsigned int pk[2][2][2];   // [jsub][isub][word]
#pragma unroll
        for (int jsub = 0; jsub < 2; jsub++)
#pragma unroll
            for (int isub = 0; isub < 2; isub++) {
                f32x4 s = {0.0f, 0.0f, 0.0f, 0.0f};
                s = __builtin_amdgcn_mfma_f32_16x16x32_bf16(ak[jsub][0], bq[isub][0], s, 0, 0, 0);
                s = __builtin_amdgcn_mfma_f32_16x16x32_bf16(ak[jsub][1], bq[isub][1], s, 0, 0, 0);
                int i = iw + isub * 16 + lr;
                int jb0 = jt + jsub * 16 + lg * 4;
                float p[4];
#pragma unroll
                for (int rg = 0; rg < 4; rg++)
                    p[rg] = (jb0 + rg <= i) ? __expf(s[rg]) * rcv[jsub][rg] : 0.0f;
                pk[jsub][isub][0] = cvt_pk_bf16(p[0], p[1]);
                pk[jsub][isub][1] = cvt_pk_bf16(p[2], p[3]);
            }

#pragma unroll
        for (int isub = 0; isub < 2; isub++) {
            int a0 = __shfl((int)pk[0][isub][0], src0);
            int a1 = __shfl((int)pk[0][isub][1], src0);
            int a2 = __shfl((int)pk[0][isub][0], src1);
            int a3 = __shfl((int)pk[0][isub][1], src1);
            int b0 = __shfl((int)pk[1][isub][0], src0);
            int b1 = __shfl((int)pk[1][isub][1], src0);
            int b2 = __shfl((int)pk[1][isub][0], src1);
            int b3 = __shfl((int)pk[1][isub][1], src1);
            int4 wv;
            wv.x = jlow ? a0 : b0;
            wv.y = jlow ? a1 : b1;
            wv.z = jlow ? a2 : b2;
            wv.w = jlow ? a3 : b3;
            short8v bp = __builtin_bit_cast(short8v, wv);
#pragma unroll
            for (int csub = 0; csub < 4; csub++)
                acc[csub][isub] = __builtin_amdgcn_mfma_f32_16x16x32_bf16(av[csub], bp, acc[csub][isub], 0, 0, 0);
        }
    }

    // epilogue: element (c = csub*16+lg*4+rg, i = iw+isub*16+lr), 8B stores
#pragma unroll
    for (int csub = 0; csub < 4; csub++)
#pragma unroll
        for (int isub = 0; isub < 2; isub++) {
            int i = iw + isub * 16 + lr;
            int c0 = csub * 16 + lg * 4;
            unsigned short t4[4];
#pragma unroll
            for (int rg = 0; rg < 4; rg++) t4[rg] = f2bf(acc[csub][isub][rg]);
            *(uint2*)&Ch[(size_t)i * HDIM + c0] = *(uint2*)t4;
        }
}

// ---------------------------------------------------------------------------
extern "C" void kernel_launch(void* const* d_in, const int* in_sizes, int n_in,
                              void* d_out, int out_size, void* d_ws, size_t ws_size,
                              hipStream_t stream)
{
    const float* H_q = (const float*)d_in[0];
    const float* H_k = (const float*)d_in[1];
    const float* H_v = (const float*)d_in[2];
    const float* W_q = (const float*)d_in[3];
    const float* b_q = (const float*)d_in[4];
    const float* W_k = (const float*)d_in[5];
    const float* b_k = (const float*)d_in[6];
    const float* W_v = (const float*)d_in[7];
    const float* b_v = (const float*)d_in[8];
    const float* W_o = (const float*)d_in[9];
    const float* b_o = (const float*)d_in[10];

    char* ws = (char*)d_ws;
    const size_t MB = (size_t)1 << 20;
    // 40.25 MB total (same high-water as round 0):
    //  [0,8)   Qb           (gemmQ -> colsum, attn)
    //  [8,16)  Kb           (gemmK -> colsum, attn)
    //  [16,24) Vt           (vtrans -> attn)
    //  [24,32) Vb then Ctx  (gemmV -> vtrans; attn -> gemmO)
    //  [32,40) Wtq/Wtk/Wtv/Wto
    //  [40,..) rcpC (256 KB)
    unsigned short* Qb  = (unsigned short*)(ws + 0 * MB);
    unsigned short* Kb  = (unsigned short*)(ws + 8 * MB);
    unsigned short* Vt  = (unsigned short*)(ws + 16 * MB);
    unsigned short* Vb  = (unsigned short*)(ws + 24 * MB);
    unsigned short* Ctx = (unsigned short*)(ws + 24 * MB);
    unsigned short* Wtq = (unsigned short*)(ws + 32 * MB);
    unsigned short* Wtk = (unsigned short*)(ws + 34 * MB);
    unsigned short* Wtv = (unsigned short*)(ws + 36 * MB);
    unsigned short* Wto = (unsigned short*)(ws + 38 * MB);
    float* rcpC = (float*)(ws + 40 * MB);

    wtrans_kernel<<<dim3(16, 16, 4), 256, 0, stream>>>(W_q, W_k, W_v, W_o, Wtq, Wtk, Wtv, Wto);

    const float scale = 0.03125f;  // 1/sqrt(1024)
    gemm_bt_kernel<false, true><<<dim3(8, 32), 256, 0, stream>>>(H_q, Wtq, b_q, scale, Qb);
    gemm_bt_kernel<false, true><<<dim3(8, 32), 256, 0, stream>>>(H_k, Wtk, b_k, scale, Kb);
    gemm_bt_kernel<false, true><<<dim3(8, 32), 256, 0, stream>>>(H_v, Wtv, b_v, 1.0f, Vb);

    vtrans_kernel<<<dim3(32, 32), 256, 0, stream>>>(Vb, Vt);
    colsum_kernel<<<dim3(32, 32), 256, 0, stream>>>(Qb, Kb, rcpC);
    attn_kernel<<<dim3(64, 32), 64, 0, stream>>>(Qb, Kb, Vt, rcpC, Ctx);

    gemm_bt_kernel<true, false><<<dim3(8, 32), 256, 0, stream>>>(Ctx, Wto, b_o, 1.0f, d_out);
}

// Round 3
// 247.961 us; speedup vs baseline: 1.3081x; 1.3081x over previous
//
#include <hip/hip_runtime.h>

#define L 2048
#define HSZ 1024
#define HDIM 64
// 32 head-panels total (N=2 batches x 16 heads), each a contiguous [2048][64]

typedef float f32x4 __attribute__((ext_vector_type(4)));
typedef short short8v __attribute__((ext_vector_type(8)));

static __device__ __forceinline__ unsigned short f2bf(float f) {
    unsigned int u = __builtin_bit_cast(unsigned int, f);
    u += 0x7FFFu + ((u >> 16) & 1u);   // RNE
    return (unsigned short)(u >> 16);
}
static __device__ __forceinline__ float bf2f(unsigned short u) {
    return __builtin_bit_cast(float, (unsigned int)u << 16);
}
static __device__ __forceinline__ unsigned int cvt_pk_bf16(float lo, float hi) {
    unsigned int r;
    asm("v_cvt_pk_bf16_f32 %0, %1, %2" : "=v"(r) : "v"(lo), "v"(hi));
    return r;
}
static __device__ __forceinline__ void gload_lds16(const void* g, void* l) {
    __builtin_amdgcn_global_load_lds(
        (const __attribute__((address_space(1))) unsigned int*)g,
        (__attribute__((address_space(3))) unsigned int*)l, 16, 0, 0);
}

// ---------------------------------------------------------------------------
// Weights: Wt4[z][n][k] = bf16(W_z[k][n]) for z in {q,k,v,o}.
// ---------------------------------------------------------------------------
__global__ __launch_bounds__(256) void wtrans_kernel(
    const float* __restrict__ W0, const float* __restrict__ W1,
    const float* __restrict__ W2, const float* __restrict__ W3,
    unsigned short* __restrict__ Wt4)
{
    const float* W;
    int z = blockIdx.z;
    if (z == 0) W = W0; else if (z == 1) W = W1; else if (z == 2) W = W2; else W = W3;
    unsigned short* T = Wt4 + (size_t)z * HSZ * HSZ;

    __shared__ __align__(16) unsigned short tl[64][72];
    int t = threadIdx.x;
    int k0 = blockIdx.y * 64, n0 = blockIdx.x * 64;

    int kl = t >> 2, nc = (t & 3) * 16;
    const float* src = W + (size_t)(k0 + kl) * HSZ + n0 + nc;
#pragma unroll
    for (int q = 0; q < 4; q++) {
        float4 v = ((const float4*)src)[q];
        tl[kl][nc + q * 4 + 0] = f2bf(v.x);
        tl[kl][nc + q * 4 + 1] = f2bf(v.y);
        tl[kl][nc + q * 4 + 2] = f2bf(v.z);
        tl[kl][nc + q * 4 + 3] = f2bf(v.w);
    }
    __syncthreads();
    int nl = t >> 2, kc = (t & 3) * 16;
    unsigned short tmp[16];
#pragma unroll
    for (int e = 0; e < 16; e++) tmp[e] = tl[kc + e][nl];
    unsigned short* dst = T + (size_t)(n0 + nl) * HSZ + k0 + kc;
    ((uint4*)dst)[0] = *(uint4*)&tmp[0];
    ((uint4*)dst)[1] = *(uint4*)&tmp[8];
}

// ---------------------------------------------------------------------------
// Convert H_q/H_k/H_v fp32 -> bf16 into contiguous Hbf[3][4096][1024].
// ---------------------------------------------------------------------------
__global__ __launch_bounds__(256) void hconv_kernel(
    const float* __restrict__ H0, const float* __restrict__ H1,
    const float* __restrict__ H2, unsigned short* __restrict__ Hbf)
{
    int z = blockIdx.y;
    const float* S = (z == 0) ? H0 : (z == 1) ? H1 : H2;
    size_t base = ((size_t)blockIdx.x * 256 + threadIdx.x) * 8;
    unsigned short* D = Hbf + (size_t)z * (4096 * 1024) + base;
    float4 a = *(const float4*)(S + base);
    float4 b = *(const float4*)(S + base + 4);
    unsigned short o[8] = {f2bf(a.x), f2bf(a.y), f2bf(a.z), f2bf(a.w),
                           f2bf(b.x), f2bf(b.y), f2bf(b.z), f2bf(b.w)};
    *(uint4*)D = *(const uint4*)o;
}

// ---------------------------------------------------------------------------
// m97-style GEMM: out[proj][4096][1024] = A[proj] @ B[proj]^T + bias, *scale.
// A,B bf16 row-major with K contiguous. global_load_lds(16B) staging, BK=32,
// 128x128 tile, 4 waves (2x2), 16 MFMA / K-step. proj = blockIdx.x>>3.
// ---------------------------------------------------------------------------
template<bool OUTF32>
__global__ __launch_bounds__(256) void gemm_glds_kernel(
    const unsigned short* __restrict__ A, const unsigned short* __restrict__ B,
    const float* __restrict__ bias0, const float* __restrict__ bias1,
    const float* __restrict__ bias2, float scale01, float scale2,
    void* __restrict__ outbase)
{
    __shared__ __align__(16) unsigned short As[128 * 32];
    __shared__ __align__(16) unsigned short Bs[128 * 32];

    int t = threadIdx.x;
    int lane = t & 63, w = t >> 6;
    int lr = lane & 15, lg = lane >> 4;
    int proj = blockIdx.x >> 3;
    int nb = (blockIdx.x & 7) * 128;
    int mb = blockIdx.y * 128;
    int wm = (w >> 1) * 64, wn = (w & 1) * 64;

    const unsigned short* Ap = A + (size_t)proj * (4096 * 1024);
    const unsigned short* Bp = B + (size_t)proj * (1024 * 1024);
    const float* bias = (proj == 0) ? bias0 : (proj == 1) ? bias1 : bias2;
    float scale = (proj < 2) ? scale01 : scale2;

    // staging: 16B chunks, 4 per 32-elem row, 512 per tile, 2 rounds of 256
    int c0 = w * 64 + lane;
    int r0 = c0 >> 2, e0 = (c0 & 3) * 8;
    int r1 = r0 + 64;
    const unsigned short* gA0 = Ap + (size_t)(mb + r0) * HSZ + e0;
    const unsigned short* gA1 = Ap + (size_t)(mb + r1) * HSZ + e0;
    const unsigned short* gB0 = Bp + (size_t)(nb + r0) * HSZ + e0;
    const unsigned short* gB1 = Bp + (size_t)(nb + r1) * HSZ + e0;
    unsigned short* lA0 = As + w * 512;          // wave-uniform LDS bases
    unsigned short* lA1 = As + 2048 + w * 512;
    unsigned short* lB0 = Bs + w * 512;
    unsigned short* lB1 = Bs + 2048 + w * 512;

    f32x4 acc[4][4] = {};

    for (int kt = 0; kt < HSZ; kt += 32) {
        gload_lds16(gA0 + kt, lA0);
        gload_lds16(gA1 + kt, lA1);
        gload_lds16(gB0 + kt, lB0);
        gload_lds16(gB1 + kt, lB1);
        __syncthreads();

        short8v af[4], bfv[4];
#pragma unroll
        for (int s = 0; s < 4; s++) {
            af[s]  = *(const short8v*)&As[(wm + s * 16 + lr) * 32 + lg * 8];
            bfv[s] = *(const short8v*)&Bs[(wn + s * 16 + lr) * 32 + lg * 8];
        }
#pragma unroll
        for (int i = 0; i < 4; i++)
#pragma unroll
            for (int j = 0; j < 4; j++)
                acc[i][j] = __builtin_amdgcn_mfma_f32_16x16x32_bf16(af[i], bfv[j], acc[i][j], 0, 0, 0);
        __syncthreads();
    }

#pragma unroll
    for (int j = 0; j < 4; j++) {
        int col = nb + wn + j * 16 + lr;
        float bv = bias[col];
#pragma unroll
        for (int i = 0; i < 4; i++) {
            int row0 = mb + wm + i * 16 + lg * 4;
#pragma unroll
            for (int rg = 0; rg < 4; rg++) {
                float v = (acc[i][j][rg] + bv) * scale;
                if (OUTF32)
                    ((float*)outbase)[(size_t)(row0 + rg) * HSZ + col] = v;
                else
                    ((unsigned short*)outbase)[(size_t)proj * (4096 * 1024) +
                                               (size_t)(row0 + rg) * HSZ + col] = f2bf(v);
            }
        }
    }
}

// ---------------------------------------------------------------------------
// Legacy fp32-A GEMM (fallback path if ws is small). Verified in R0/R1.
// ---------------------------------------------------------------------------
template<bool ABF16, bool OUTBF16>
__global__ __launch_bounds__(256) void gemm_bt_kernel(
    const void* __restrict__ Aptr, const unsigned short* __restrict__ Bt,
    const float* __restrict__ bias, float scale, void* __restrict__ outp)
{
    __shared__ __align__(16) unsigned short As[128][40];
    __shared__ __align__(16) unsigned short Bs[128][40];

    int t = threadIdx.x;
    int lane = t & 63, w = t >> 6;
    int lr = lane & 15, lg = lane >> 4;
    int mb = blockIdx.y * 128, nb = blockIdx.x * 128;
    int wm = (w >> 1) * 64, wn = (w & 1) * 64;
    int r = t >> 1, cc = (t & 1) * 16;

    f32x4 acc[4][4] = {};

    for (int kt = 0; kt < HSZ; kt += 32) {
        if (ABF16) {
            const unsigned short* A = (const unsigned short*)Aptr + (size_t)(mb + r) * HSZ + kt + cc;
            *(uint4*)&As[r][cc]     = ((const uint4*)A)[0];
            *(uint4*)&As[r][cc + 8] = ((const uint4*)A)[1];
        } else {
            const float* A = (const float*)Aptr + (size_t)(mb + r) * HSZ + kt + cc;
            unsigned short tmp[16];
#pragma unroll
            for (int q = 0; q < 4; q++) {
                float4 v = ((const float4*)A)[q];
                tmp[q * 4 + 0] = f2bf(v.x); tmp[q * 4 + 1] = f2bf(v.y);
                tmp[q * 4 + 2] = f2bf(v.z); tmp[q * 4 + 3] = f2bf(v.w);
            }
            *(uint4*)&As[r][cc]     = *(uint4*)&tmp[0];
            *(uint4*)&As[r][cc + 8] = *(uint4*)&tmp[8];
        }
        {
            const unsigned short* B = Bt + (size_t)(nb + r) * HSZ + kt + cc;
            *(uint4*)&Bs[r][cc]     = ((const uint4*)B)[0];
            *(uint4*)&Bs[r][cc + 8] = ((const uint4*)B)[1];
        }
        __syncthreads();

        short8v af[4], bf[4];
#pragma unroll
        for (int s = 0; s < 4; s++) af[s] = *(const short8v*)&As[wm + s * 16 + lr][8 * lg];
#pragma unroll
        for (int s = 0; s < 4; s++) bf[s] = *(const short8v*)&Bs[wn + s * 16 + lr][8 * lg];
#pragma unroll
        for (int i = 0; i < 4; i++)
#pragma unroll
            for (int j = 0; j < 4; j++)
                acc[i][j] = __builtin_amdgcn_mfma_f32_16x16x32_bf16(af[i], bf[j], acc[i][j], 0, 0, 0);
        __syncthreads();
    }

#pragma unroll
    for (int j = 0; j < 4; j++) {
        int col = nb + wn + j * 16 + lr;
        float bv = bias[col];
#pragma unroll
        for (int i = 0; i < 4; i++) {
            int row0 = mb + wm + i * 16 + lg * 4;
#pragma unroll
            for (int rg = 0; rg < 4; rg++) {
                float v = (acc[i][j][rg] + bv) * scale;
                if (OUTBF16)
                    ((unsigned short*)outp)[(size_t)(row0 + rg) * HSZ + col] = f2bf(v);
                else
                    ((float*)outp)[(size_t)(row0 + rg) * HSZ + col] = v;
            }
        }
    }
}

// ---------------------------------------------------------------------------
// Phase 1: rcpC[head][j] = 1 / sum_{i>=j} exp(S_ij). S^T = mfma(K,Q),
// 1-deep prefetch of the next Q i-block.
// ---------------------------------------------------------------------------
__global__ __launch_bounds__(256) void colsum_kernel(
    const unsigned short* __restrict__ Qb, const unsigned short* __restrict__ Kb,
    float* __restrict__ rcpC)
{
    int head = blockIdx.y;
    int jb = blockIdx.x * 64;
    const unsigned short* Qh = Qb + (size_t)head * L * HDIM;
    const unsigned short* Kh = Kb + (size_t)head * L * HDIM;
    int t = threadIdx.x, lane = t & 63, w = t >> 6;
    int lr = lane & 15, lg = lane >> 4;

    short8v af[4][2];
#pragma unroll
    for (int sj = 0; sj < 4; sj++)
#pragma unroll
        for (int kk = 0; kk < 2; kk++)
            af[sj][kk] = *(const short8v*)&Kh[(size_t)(jb + sj * 16 + lr) * HDIM + kk * 32 + 8 * lg];

    float accs[4][4] = {};

    int it0 = jb + w * 16;
    short8v bc0 = *(const short8v*)&Qh[(size_t)(it0 + lr) * HDIM + 8 * lg];
    short8v bc1 = *(const short8v*)&Qh[(size_t)(it0 + lr) * HDIM + 32 + 8 * lg];

    for (int it = it0; it < L; it += 64) {
        int itn = (it + 64 < L) ? it + 64 : it;
        short8v bn0 = *(const short8v*)&Qh[(size_t)(itn + lr) * HDIM + 8 * lg];
        short8v bn1 = *(const short8v*)&Qh[(size_t)(itn + lr) * HDIM + 32 + 8 * lg];
        int i = it + lr;
#pragma unroll
        for (int sj = 0; sj < 4; sj++) {
            f32x4 d = {0.0f, 0.0f, 0.0f, 0.0f};
            d = __builtin_amdgcn_mfma_f32_16x16x32_bf16(af[sj][0], bc0, d, 0, 0, 0);
            d = __builtin_amdgcn_mfma_f32_16x16x32_bf16(af[sj][1], bc1, d, 0, 0, 0);
#pragma unroll
            for (int rg = 0; rg < 4; rg++) {
                int j = jb + sj * 16 + lg * 4 + rg;
                if (i >= j) accs[sj][rg] += __expf(d[rg]);
            }
        }
        bc0 = bn0; bc1 = bn1;
    }

    __shared__ float part[4][64];
#pragma unroll
    for (int sj = 0; sj < 4; sj++)
#pragma unroll
        for (int rg = 0; rg < 4; rg++) {
            float v = accs[sj][rg];
            v += __shfl_xor(v, 1); v += __shfl_xor(v, 2);
            v += __shfl_xor(v, 4); v += __shfl_xor(v, 8);
            if (lr == 0) part[w][sj * 16 + lg * 4 + rg] = v;
        }
    __syncthreads();
    if (t < 64) {
        float s = part[0][t] + part[1][t] + part[2][t] + part[3][t];
        rcpC[(size_t)head * L + jb + t] = 1.0f / s;
    }
}

// ---------------------------------------------------------------------------
// V transpose with rcpC folded: Vt[p][c][j] = bf16(V[p][j][c] * rcpC[p][j]).
// ---------------------------------------------------------------------------
__global__ __launch_bounds__(256) void vtrans_kernel(
    const unsigned short* __restrict__ Vb, const float* __restrict__ rcpC,
    unsigned short* __restrict__ Vt)
{
    int p = blockIdx.y;
    int j0 = blockIdx.x * 64;
    const unsigned short* Vp = Vb + (size_t)p * L * HDIM;
    unsigned short* Tp = Vt + (size_t)p * HDIM * L;
    __shared__ __align__(16) unsigned short tl[64][72];
    int t = threadIdx.x;
    int jl = t >> 2, c0 = (t & 3) * 16;
    float rcv = rcpC[(size_t)p * L + j0 + jl];
    const unsigned short* src = Vp + (size_t)(j0 + jl) * HDIM + c0;
    unsigned short raw[16];
    *(uint4*)&raw[0] = ((const uint4*)src)[0];
    *(uint4*)&raw[8] = ((const uint4*)src)[1];
#pragma unroll
    for (int e = 0; e < 16; e++) tl[jl][c0 + e] = f2bf(bf2f(raw[e]) * rcv);
    __syncthreads();
    int cl = t >> 2, jc = (t & 3) * 16;
    unsigned short tmp[16];
#pragma unroll
    for (int e = 0; e < 16; e++) tmp[e] = tl[jc + e][cl];
    unsigned short* dst = Tp + (size_t)cl * L + j0 + jc;
    ((uint4*)dst)[0] = *(uint4*)&tmp[0];
    ((uint4*)dst)[1] = *(uint4*)&tmp[8];
}

// ---------------------------------------------------------------------------
// Phase 2: one wave per 32 q-rows, zero LDS/barriers, 1-deep K/V prefetch.
// rcpC pre-folded into Vt, so P = exp(S) raw.
// ---------------------------------------------------------------------------
struct WBuf { short8v ak[2][2]; short8v av[4]; };

__global__ __launch_bounds__(64) void attn_kernel(
    const unsigned short* __restrict__ Qb, const unsigned short* __restrict__ Kb,
    const unsigned short* __restrict__ Vt, unsigned short* __restrict__ Ctx)
{
    int head = blockIdx.y;
    int tile = blockIdx.x;          // 32 q-rows per tile
    int iw = tile * 32;
    const unsigned short* Qh = Qb + (size_t)head * L * HDIM;
    const unsigned short* Kh = Kb + (size_t)head * L * HDIM;
    const unsigned short* Vh = Vt + (size_t)head * HDIM * L;   // [64][2048]
    unsigned short* Ch = Ctx + (size_t)head * L * HDIM;

    int lane = threadIdx.x;
    int lr = lane & 15, lg = lane >> 4;
    int src0 = ((lane & 16) << 1) + lr;
    int src1 = src0 + 16;
    bool jlow = (lg < 2);

    short8v bq[2][2];
#pragma unroll
    for (int isub = 0; isub < 2; isub++)
#pragma unroll
        for (int kd = 0; kd < 2; kd++)
            bq[isub][kd] = *(const short8v*)&Qh[(size_t)(iw + isub * 16 + lr) * HDIM + kd * 32 + 8 * lg];

    f32x4 acc[4][2] = {};

    auto loadWin = [&](int w2, WBuf& b) {
        int jt = w2 * 32;
#pragma unroll
        for (int jsub = 0; jsub < 2; jsub++)
#pragma unroll
            for (int kd = 0; kd < 2; kd++)
                b.ak[jsub][kd] = *(const short8v*)&Kh[(size_t)(jt + jsub * 16 + lr) * HDIM + kd * 32 + 8 * lg];
#pragma unroll
        for (int csub = 0; csub < 4; csub++)
            b.av[csub] = *(const short8v*)&Vh[(size_t)(csub * 16 + lr) * L + jt + 8 * lg];
    };

    auto computeWin = [&](int wnd, const WBuf& b) {
        unsigned int pk[2][2][2];
#pragma unroll
        for (int jsub = 0; jsub < 2; jsub++)
#pragma unroll
            for (int isub = 0; isub < 2; isub++) {
                f32x4 s = {0.0f, 0.0f, 0.0f, 0.0f};
                s = __builtin_amdgcn_mfma_f32_16x16x32_bf16(b.ak[jsub][0], bq[isub][0], s, 0, 0, 0);
                s = __builtin_amdgcn_mfma_f32_16x16x32_bf16(b.ak[jsub][1], bq[isub][1], s, 0, 0, 0);
                int i = iw + isub * 16 + lr;
                int jb0 = wnd * 32 + jsub * 16 + lg * 4;
                float p[4];
#pragma unroll
                for (int rg = 0; rg < 4; rg++)
                    p[rg] = (jb0 + rg <= i) ? __expf(s[rg]) : 0.0f;
                pk[jsub][isub][0] = cvt_pk_bf16(p[0], p[1]);
                pk[jsub][isub][1] = cvt_pk_bf16(p[2], p[3]);
            }
        __builtin_amdgcn_s_setprio(1);
#pragma unroll
        for (int isub = 0; isub < 2; isub++) {
            int a0 = __shfl((int)pk[0][isub][0], src0);
            int a1 = __shfl((int)pk[0][isub][1], src0);
            int a2 = __shfl((int)pk[0][isub][0], src1);
            int a3 = __shfl((int)pk[0][isub][1], src1);
            int b0 = __shfl((int)pk[1][isub][0], src0);
            int b1 = __shfl((int)pk[1][isub][1], src0);
            int b2 = __shfl((int)pk[1][isub][0], src1);
            int b3 = __shfl((int)pk[1][isub][1], src1);
            int4 wv;
            wv.x = jlow ? a0 : b0;
            wv.y = jlow ? a1 : b1;
            wv.z = jlow ? a2 : b2;
            wv.w = jlow ? a3 : b3;
            short8v bp = __builtin_bit_cast(short8v, wv);
#pragma unroll
            for (int csub = 0; csub < 4; csub++)
                acc[csub][isub] = __builtin_amdgcn_mfma_f32_16x16x32_bf16(b.av[csub], bp, acc[csub][isub], 0, 0, 0);
        }
        __builtin_amdgcn_s_setprio(0);
    };

    WBuf A, B;
    loadWin(0, A);
    int wnd = 0;
    for (; wnd + 1 <= tile; wnd += 2) {
        loadWin(wnd + 1, B);
        computeWin(wnd, A);
        int n2 = (wnd + 2 <= tile) ? wnd + 2 : wnd + 1;
        loadWin(n2, A);
        computeWin(wnd + 1, B);
    }
    if (wnd <= tile) computeWin(wnd, A);

#pragma unroll
    for (int csub = 0; csub < 4; csub++)
#pragma unroll
        for (int isub = 0; isub < 2; isub++) {
            int i = iw + isub * 16 + lr;
            int c0 = csub * 16 + lg * 4;
            unsigned short t4[4];
#pragma unroll
            for (int rg = 0; rg < 4; rg++) t4[rg] = f2bf(acc[csub][isub][rg]);
            *(uint2*)&Ch[(size_t)i * HDIM + c0] = *(uint2*)t4;
        }
}

// ---------------------------------------------------------------------------
extern "C" void kernel_launch(void* const* d_in, const int* in_sizes, int n_in,
                              void* d_out, int out_size, void* d_ws, size_t ws_size,
                              hipStream_t stream)
{
    const float* H_q = (const float*)d_in[0];
    const float* H_k = (const float*)d_in[1];
    const float* H_v = (const float*)d_in[2];
    const float* W_q = (const float*)d_in[3];
    const float* b_q = (const float*)d_in[4];
    const float* W_k = (const float*)d_in[5];
    const float* b_k = (const float*)d_in[6];
    const float* W_v = (const float*)d_in[7];
    const float* b_v = (const float*)d_in[8];
    const float* W_o = (const float*)d_in[9];
    const float* b_o = (const float*)d_in[10];

    char* ws = (char*)d_ws;
    const size_t MB = (size_t)1 << 20;
    const float scale = 0.03125f;  // 1/sqrt(1024)

    if (ws_size >= 60 * MB) {
        // Layout (56.3 MB high-water):
        //  [0,24)  Hbf (hconv -> QKV gemm); then Vt at [0,8), Ctx at [8,16)
        //  [24,32) Wt4
        //  [32,56) Qb, Kb, Vb
        //  [56,..) rcpC
        unsigned short* Hbf = (unsigned short*)(ws);
        unsigned short* Vt  = (unsigned short*)(ws);
        unsigned short* Ctx = (unsigned short*)(ws + 8 * MB);
        unsigned short* Wt4 = (unsigned short*)(ws + 24 * MB);
        unsigned short* Qb  = (unsigned short*)(ws + 32 * MB);
        unsigned short* Kb  = (unsigned short*)(ws + 40 * MB);
        unsigned short* Vb  = (unsigned short*)(ws + 48 * MB);
        float* rcpC = (float*)(ws + 56 * MB);

        wtrans_kernel<<<dim3(16, 16, 4), 256, 0, stream>>>(W_q, W_k, W_v, W_o, Wt4);
        hconv_kernel<<<dim3(2048, 3), 256, 0, stream>>>(H_q, H_k, H_v, Hbf);
        gemm_glds_kernel<false><<<dim3(24, 32), 256, 0, stream>>>(
            Hbf, Wt4, b_q, b_k, b_v, scale, 1.0f, Qb);
        colsum_kernel<<<dim3(32, 32), 256, 0, stream>>>(Qb, Kb, rcpC);
        vtrans_kernel<<<dim3(32, 32), 256, 0, stream>>>(Vb, rcpC, Vt);
        attn_kernel<<<dim3(64, 32), 64, 0, stream>>>(Qb, Kb, Vt, Ctx);
        gemm_glds_kernel<true><<<dim3(8, 32), 256, 0, stream>>>(
            Ctx, Wt4 + (size_t)3 * 1024 * 1024, b_o, b_o, b_o, 1.0f, 1.0f, d_out);
    } else {
        // Fallback (40.25 MB, proven): legacy fp32-A GEMMs.
        unsigned short* Qb  = (unsigned short*)(ws + 0 * MB);
        unsigned short* Kb  = (unsigned short*)(ws + 8 * MB);
        unsigned short* Vt  = (unsigned short*)(ws + 16 * MB);
        unsigned short* Vb  = (unsigned short*)(ws + 24 * MB);
        unsigned short* Ctx = (unsigned short*)(ws + 24 * MB);
        unsigned short* Wt4 = (unsigned short*)(ws + 32 * MB);
        float* rcpC = (float*)(ws + 40 * MB);

        wtrans_kernel<<<dim3(16, 16, 4), 256, 0, stream>>>(W_q, W_k, W_v, W_o, Wt4);
        gemm_bt_kernel<false, true><<<dim3(8, 32), 256, 0, stream>>>(H_q, Wt4, b_q, scale, Qb);
        gemm_bt_kernel<false, true><<<dim3(8, 32), 256, 0, stream>>>(H_k, Wt4 + (size_t)1024 * 1024, b_k, scale, Kb);
        gemm_bt_kernel<false, true><<<dim3(8, 32), 256, 0, stream>>>(H_v, Wt4 + (size_t)2 * 1024 * 1024, b_v, 1.0f, Vb);
        colsum_kernel<<<dim3(32, 32), 256, 0, stream>>>(Qb, Kb, rcpC);
        vtrans_kernel<<<dim3(32, 32), 256, 0, stream>>>(Vb, rcpC, Vt);
        attn_kernel<<<dim3(64, 32), 64, 0, stream>>>(Qb, Kb, Vt, Ctx);
        gemm_bt_kernel<true, false><<<dim3(8, 32), 256, 0, stream>>>(Ctx, Wt4 + (size_t)3 * 1024 * 1024, b_o, 1.0f, d_out);
    }
}

// Round 4
// 224.499 us; speedup vs baseline: 1.4448x; 1.1045x over previous
//
#include <hip/hip_runtime.h>

#define L 2048
#define HSZ 1024
#define HDIM 64
// 32 head-panels total (N=2 batches x 16 heads), each a contiguous [2048][64]

typedef float f32x4 __attribute__((ext_vector_type(4)));
typedef short short8v __attribute__((ext_vector_type(8)));

static __device__ __forceinline__ unsigned short f2bf(float f) {
    unsigned int u = __builtin_bit_cast(unsigned int, f);
    u += 0x7FFFu + ((u >> 16) & 1u);   // RNE
    return (unsigned short)(u >> 16);
}
static __device__ __forceinline__ float bf2f(unsigned short u) {
    return __builtin_bit_cast(float, (unsigned int)u << 16);
}
static __device__ __forceinline__ unsigned int cvt_pk_bf16(float lo, float hi) {
    unsigned int r;
    asm("v_cvt_pk_bf16_f32 %0, %1, %2" : "=v"(r) : "v"(lo), "v"(hi));
    return r;
}
static __device__ __forceinline__ void gload_lds16(const void* g, void* l) {
    __builtin_amdgcn_global_load_lds(
        (const __attribute__((address_space(1))) unsigned int*)g,
        (__attribute__((address_space(3))) unsigned int*)l, 16, 0, 0);
}

// ---------------------------------------------------------------------------
// Weights: Wt4[z][n][k] = bf16(W_z[k][n]) for z in {q,k,v,o}.
// ---------------------------------------------------------------------------
__global__ __launch_bounds__(256) void wtrans_kernel(
    const float* __restrict__ W0, const float* __restrict__ W1,
    const float* __restrict__ W2, const float* __restrict__ W3,
    unsigned short* __restrict__ Wt4)
{
    const float* W;
    int z = blockIdx.z;
    if (z == 0) W = W0; else if (z == 1) W = W1; else if (z == 2) W = W2; else W = W3;
    unsigned short* T = Wt4 + (size_t)z * HSZ * HSZ;

    __shared__ __align__(16) unsigned short tl[64][72];
    int t = threadIdx.x;
    int k0 = blockIdx.y * 64, n0 = blockIdx.x * 64;

    int kl = t >> 2, nc = (t & 3) * 16;
    const float* src = W + (size_t)(k0 + kl) * HSZ + n0 + nc;
#pragma unroll
    for (int q = 0; q < 4; q++) {
        float4 v = ((const float4*)src)[q];
        tl[kl][nc + q * 4 + 0] = f2bf(v.x);
        tl[kl][nc + q * 4 + 1] = f2bf(v.y);
        tl[kl][nc + q * 4 + 2] = f2bf(v.z);
        tl[kl][nc + q * 4 + 3] = f2bf(v.w);
    }
    __syncthreads();
    int nl = t >> 2, kc = (t & 3) * 16;
    unsigned short tmp[16];
#pragma unroll
    for (int e = 0; e < 16; e++) tmp[e] = tl[kc + e][nl];
    unsigned short* dst = T + (size_t)(n0 + nl) * HSZ + k0 + kc;
    ((uint4*)dst)[0] = *(uint4*)&tmp[0];
    ((uint4*)dst)[1] = *(uint4*)&tmp[8];
}

// ---------------------------------------------------------------------------
// Convert H_q/H_k/H_v fp32 -> bf16 into contiguous Hbf[3][4096][1024].
// ---------------------------------------------------------------------------
__global__ __launch_bounds__(256) void hconv_kernel(
    const float* __restrict__ H0, const float* __restrict__ H1,
    const float* __restrict__ H2, unsigned short* __restrict__ Hbf)
{
    int z = blockIdx.y;
    const float* S = (z == 0) ? H0 : (z == 1) ? H1 : H2;
    size_t base = ((size_t)blockIdx.x * 256 + threadIdx.x) * 8;
    unsigned short* D = Hbf + (size_t)z * (4096 * 1024) + base;
    float4 a = *(const float4*)(S + base);
    float4 b = *(const float4*)(S + base + 4);
    unsigned short o[8] = {f2bf(a.x), f2bf(a.y), f2bf(a.z), f2bf(a.w),
                           f2bf(b.x), f2bf(b.y), f2bf(b.z), f2bf(b.w)};
    *(uint4*)D = *(const uint4*)o;
}

// ---------------------------------------------------------------------------
// m97-style GEMM: out[proj][4096][1024] = A[proj] @ B[proj]^T + bias, *scale.
// ---------------------------------------------------------------------------
template<bool OUTF32>
__global__ __launch_bounds__(256) void gemm_glds_kernel(
    const unsigned short* __restrict__ A, const unsigned short* __restrict__ B,
    const float* __restrict__ bias0, const float* __restrict__ bias1,
    const float* __restrict__ bias2, float scale01, float scale2,
    void* __restrict__ outbase)
{
    __shared__ __align__(16) unsigned short As[128 * 32];
    __shared__ __align__(16) unsigned short Bs[128 * 32];

    int t = threadIdx.x;
    int lane = t & 63, w = t >> 6;
    int lr = lane & 15, lg = lane >> 4;
    int proj = blockIdx.x >> 3;
    int nb = (blockIdx.x & 7) * 128;
    int mb = blockIdx.y * 128;
    int wm = (w >> 1) * 64, wn = (w & 1) * 64;

    const unsigned short* Ap = A + (size_t)proj * (4096 * 1024);
    const unsigned short* Bp = B + (size_t)proj * (1024 * 1024);
    const float* bias = (proj == 0) ? bias0 : (proj == 1) ? bias1 : bias2;
    float scale = (proj < 2) ? scale01 : scale2;

    int c0 = w * 64 + lane;
    int r0 = c0 >> 2, e0 = (c0 & 3) * 8;
    int r1 = r0 + 64;
    const unsigned short* gA0 = Ap + (size_t)(mb + r0) * HSZ + e0;
    const unsigned short* gA1 = Ap + (size_t)(mb + r1) * HSZ + e0;
    const unsigned short* gB0 = Bp + (size_t)(nb + r0) * HSZ + e0;
    const unsigned short* gB1 = Bp + (size_t)(nb + r1) * HSZ + e0;
    unsigned short* lA0 = As + w * 512;
    unsigned short* lA1 = As + 2048 + w * 512;
    unsigned short* lB0 = Bs + w * 512;
    unsigned short* lB1 = Bs + 2048 + w * 512;

    f32x4 acc[4][4] = {};

    for (int kt = 0; kt < HSZ; kt += 32) {
        gload_lds16(gA0 + kt, lA0);
        gload_lds16(gA1 + kt, lA1);
        gload_lds16(gB0 + kt, lB0);
        gload_lds16(gB1 + kt, lB1);
        __syncthreads();

        short8v af[4], bfv[4];
#pragma unroll
        for (int s = 0; s < 4; s++) {
            af[s]  = *(const short8v*)&As[(wm + s * 16 + lr) * 32 + lg * 8];
            bfv[s] = *(const short8v*)&Bs[(wn + s * 16 + lr) * 32 + lg * 8];
        }
#pragma unroll
        for (int i = 0; i < 4; i++)
#pragma unroll
            for (int j = 0; j < 4; j++)
                acc[i][j] = __builtin_amdgcn_mfma_f32_16x16x32_bf16(af[i], bfv[j], acc[i][j], 0, 0, 0);
        __syncthreads();
    }

#pragma unroll
    for (int j = 0; j < 4; j++) {
        int col = nb + wn + j * 16 + lr;
        float bv = bias[col];
#pragma unroll
        for (int i = 0; i < 4; i++) {
            int row0 = mb + wm + i * 16 + lg * 4;
#pragma unroll
            for (int rg = 0; rg < 4; rg++) {
                float v = (acc[i][j][rg] + bv) * scale;
                if (OUTF32)
                    ((float*)outbase)[(size_t)(row0 + rg) * HSZ + col] = v;
                else
                    ((unsigned short*)outbase)[(size_t)proj * (4096 * 1024) +
                                               (size_t)(row0 + rg) * HSZ + col] = f2bf(v);
            }
        }
    }
}

// ---------------------------------------------------------------------------
// Legacy fp32-A GEMM (fallback path if ws is small).
// ---------------------------------------------------------------------------
template<bool ABF16, bool OUTBF16>
__global__ __launch_bounds__(256) void gemm_bt_kernel(
    const void* __restrict__ Aptr, const unsigned short* __restrict__ Bt,
    const float* __restrict__ bias, float scale, void* __restrict__ outp)
{
    __shared__ __align__(16) unsigned short As[128][40];
    __shared__ __align__(16) unsigned short Bs[128][40];

    int t = threadIdx.x;
    int lane = t & 63, w = t >> 6;
    int lr = lane & 15, lg = lane >> 4;
    int mb = blockIdx.y * 128, nb = blockIdx.x * 128;
    int wm = (w >> 1) * 64, wn = (w & 1) * 64;
    int r = t >> 1, cc = (t & 1) * 16;

    f32x4 acc[4][4] = {};

    for (int kt = 0; kt < HSZ; kt += 32) {
        if (ABF16) {
            const unsigned short* A = (const unsigned short*)Aptr + (size_t)(mb + r) * HSZ + kt + cc;
            *(uint4*)&As[r][cc]     = ((const uint4*)A)[0];
            *(uint4*)&As[r][cc + 8] = ((const uint4*)A)[1];
        } else {
            const float* A = (const float*)Aptr + (size_t)(mb + r) * HSZ + kt + cc;
            unsigned short tmp[16];
#pragma unroll
            for (int q = 0; q < 4; q++) {
                float4 v = ((const float4*)A)[q];
                tmp[q * 4 + 0] = f2bf(v.x); tmp[q * 4 + 1] = f2bf(v.y);
                tmp[q * 4 + 2] = f2bf(v.z); tmp[q * 4 + 3] = f2bf(v.w);
            }
            *(uint4*)&As[r][cc]     = *(uint4*)&tmp[0];
            *(uint4*)&As[r][cc + 8] = *(uint4*)&tmp[8];
        }
        {
            const unsigned short* B = Bt + (size_t)(nb + r) * HSZ + kt + cc;
            *(uint4*)&Bs[r][cc]     = ((const uint4*)B)[0];
            *(uint4*)&Bs[r][cc + 8] = ((const uint4*)B)[1];
        }
        __syncthreads();

        short8v af[4], bf[4];
#pragma unroll
        for (int s = 0; s < 4; s++) af[s] = *(const short8v*)&As[wm + s * 16 + lr][8 * lg];
#pragma unroll
        for (int s = 0; s < 4; s++) bf[s] = *(const short8v*)&Bs[wn + s * 16 + lr][8 * lg];
#pragma unroll
        for (int i = 0; i < 4; i++)
#pragma unroll
            for (int j = 0; j < 4; j++)
                acc[i][j] = __builtin_amdgcn_mfma_f32_16x16x32_bf16(af[i], bf[j], acc[i][j], 0, 0, 0);
        __syncthreads();
    }

#pragma unroll
    for (int j = 0; j < 4; j++) {
        int col = nb + wn + j * 16 + lr;
        float bv = bias[col];
#pragma unroll
        for (int i = 0; i < 4; i++) {
            int row0 = mb + wm + i * 16 + lg * 4;
#pragma unroll
            for (int rg = 0; rg < 4; rg++) {
                float v = (acc[i][j][rg] + bv) * scale;
                if (OUTBF16)
                    ((unsigned short*)outp)[(size_t)(row0 + rg) * HSZ + col] = f2bf(v);
                else
                    ((float*)outp)[(size_t)(row0 + rg) * HSZ + col] = v;
            }
        }
    }
}

// ---------------------------------------------------------------------------
// Phase 1: rcpC[head][j] = 1 / sum_{i>=j} exp(S_ij). S^T = mfma(K,Q).
// 1D grid (1024) with XCD-aware remap: 4 heads pinned per XCD so K/Q panels
// stay L2-resident (2 MB working set < 4 MB per-XCD L2).
// ---------------------------------------------------------------------------
__global__ __launch_bounds__(256) void colsum_kernel(
    const unsigned short* __restrict__ Qb, const unsigned short* __restrict__ Kb,
    float* __restrict__ rcpC)
{
    int raw = blockIdx.x;
    int xcd = raw & 7, idx = raw >> 3;        // idx in [0,128)
    int head = xcd * 4 + (idx >> 5);          // 4 heads per XCD
    int jb = (idx & 31) * 64;                 // jb=0 (most work) starts first
    const unsigned short* Qh = Qb + (size_t)head * L * HDIM;
    const unsigned short* Kh = Kb + (size_t)head * L * HDIM;
    int t = threadIdx.x, lane = t & 63, w = t >> 6;
    int lr = lane & 15, lg = lane >> 4;

    short8v af[4][2];
#pragma unroll
    for (int sj = 0; sj < 4; sj++)
#pragma unroll
        for (int kk = 0; kk < 2; kk++)
            af[sj][kk] = *(const short8v*)&Kh[(size_t)(jb + sj * 16 + lr) * HDIM + kk * 32 + 8 * lg];

    float accs[4][4] = {};

    int it0 = jb + w * 16;
    short8v bc0 = *(const short8v*)&Qh[(size_t)(it0 + lr) * HDIM + 8 * lg];
    short8v bc1 = *(const short8v*)&Qh[(size_t)(it0 + lr) * HDIM + 32 + 8 * lg];

    for (int it = it0; it < L; it += 64) {
        int itn = (it + 64 < L) ? it + 64 : it;
        short8v bn0 = *(const short8v*)&Qh[(size_t)(itn + lr) * HDIM + 8 * lg];
        short8v bn1 = *(const short8v*)&Qh[(size_t)(itn + lr) * HDIM + 32 + 8 * lg];
        int i = it + lr;
#pragma unroll
        for (int sj = 0; sj < 4; sj++) {
            f32x4 d = {0.0f, 0.0f, 0.0f, 0.0f};
            d = __builtin_amdgcn_mfma_f32_16x16x32_bf16(af[sj][0], bc0, d, 0, 0, 0);
            d = __builtin_amdgcn_mfma_f32_16x16x32_bf16(af[sj][1], bc1, d, 0, 0, 0);
#pragma unroll
            for (int rg = 0; rg < 4; rg++) {
                int j = jb + sj * 16 + lg * 4 + rg;
                if (i >= j) accs[sj][rg] += __expf(d[rg]);
            }
        }
        bc0 = bn0; bc1 = bn1;
    }

    __shared__ float part[4][64];
#pragma unroll
    for (int sj = 0; sj < 4; sj++)
#pragma unroll
        for (int rg = 0; rg < 4; rg++) {
            float v = accs[sj][rg];
            v += __shfl_xor(v, 1); v += __shfl_xor(v, 2);
            v += __shfl_xor(v, 4); v += __shfl_xor(v, 8);
            if (lr == 0) part[w][sj * 16 + lg * 4 + rg] = v;
        }
    __syncthreads();
    if (t < 64) {
        float s = part[0][t] + part[1][t] + part[2][t] + part[3][t];
        rcpC[(size_t)head * L + jb + t] = 1.0f / s;
    }
}

// ---------------------------------------------------------------------------
// V transpose with rcpC folded: Vt[p][c][j] = bf16(V[p][j][c] * rcpC[p][j]).
// ---------------------------------------------------------------------------
__global__ __launch_bounds__(256) void vtrans_kernel(
    const unsigned short* __restrict__ Vb, const float* __restrict__ rcpC,
    unsigned short* __restrict__ Vt)
{
    int p = blockIdx.y;
    int j0 = blockIdx.x * 64;
    const unsigned short* Vp = Vb + (size_t)p * L * HDIM;
    unsigned short* Tp = Vt + (size_t)p * HDIM * L;
    __shared__ __align__(16) unsigned short tl[64][72];
    int t = threadIdx.x;
    int jl = t >> 2, c0 = (t & 3) * 16;
    float rcv = rcpC[(size_t)p * L + j0 + jl];
    const unsigned short* src = Vp + (size_t)(j0 + jl) * HDIM + c0;
    unsigned short raw[16];
    *(uint4*)&raw[0] = ((const uint4*)src)[0];
    *(uint4*)&raw[8] = ((const uint4*)src)[1];
#pragma unroll
    for (int e = 0; e < 16; e++) tl[jl][c0 + e] = f2bf(bf2f(raw[e]) * rcv);
    __syncthreads();
    int cl = t >> 2, jc = (t & 3) * 16;
    unsigned short tmp[16];
#pragma unroll
    for (int e = 0; e < 16; e++) tmp[e] = tl[jc + e][cl];
    unsigned short* dst = Tp + (size_t)cl * L + j0 + jc;
    ((uint4*)dst)[0] = *(uint4*)&tmp[0];
    ((uint4*)dst)[1] = *(uint4*)&tmp[8];
}

// ---------------------------------------------------------------------------
// Phase 2: one wave per 32 q-rows, zero LDS/barriers, 1-deep K/V prefetch.
// 1D grid (2048) with XCD-aware remap: all 64 i-tiles of a head on ONE XCD
// (4 heads/XCD, ~3 MB working set < 4 MB L2) so K/V reads are L2 hits.
// Tiles ordered big-first (LPT).
// ---------------------------------------------------------------------------
struct WBuf { short8v ak[2][2]; short8v av[4]; };

__global__ __launch_bounds__(64) void attn_kernel(
    const unsigned short* __restrict__ Qb, const unsigned short* __restrict__ Kb,
    const unsigned short* __restrict__ Vt, unsigned short* __restrict__ Ctx)
{
    int raw = blockIdx.x;
    int xcd = raw & 7, idx = raw >> 3;        // idx in [0,256)
    int head = xcd * 4 + (idx >> 6);          // 4 heads per XCD
    int tile = 63 - (idx & 63);               // LPT: big tiles first
    int iw = tile * 32;
    const unsigned short* Qh = Qb + (size_t)head * L * HDIM;
    const unsigned short* Kh = Kb + (size_t)head * L * HDIM;
    const unsigned short* Vh = Vt + (size_t)head * HDIM * L;   // [64][2048]
    unsigned short* Ch = Ctx + (size_t)head * L * HDIM;

    int lane = threadIdx.x;
    int lr = lane & 15, lg = lane >> 4;
    int src0 = ((lane & 16) << 1) + lr;
    int src1 = src0 + 16;
    bool jlow = (lg < 2);

    short8v bq[2][2];
#pragma unroll
    for (int isub = 0; isub < 2; isub++)
#pragma unroll
        for (int kd = 0; kd < 2; kd++)
            bq[isub][kd] = *(const short8v*)&Qh[(size_t)(iw + isub * 16 + lr) * HDIM + kd * 32 + 8 * lg];

    f32x4 acc[4][2] = {};

    auto loadWin = [&](int w2, WBuf& b) {
        int jt = w2 * 32;
#pragma unroll
        for (int jsub = 0; jsub < 2; jsub++)
#pragma unroll
            for (int kd = 0; kd < 2; kd++)
                b.ak[jsub][kd] = *(const short8v*)&Kh[(size_t)(jt + jsub * 16 + lr) * HDIM + kd * 32 + 8 * lg];
#pragma unroll
        for (int csub = 0; csub < 4; csub++)
            b.av[csub] = *(const short8v*)&Vh[(size_t)(csub * 16 + lr) * L + jt + 8 * lg];
    };

    auto computeWin = [&](int wnd, const WBuf& b) {
        unsigned int pk[2][2][2];
#pragma unroll
        for (int jsub = 0; jsub < 2; jsub++)
#pragma unroll
            for (int isub = 0; isub < 2; isub++) {
                f32x4 s = {0.0f, 0.0f, 0.0f, 0.0f};
                s = __builtin_amdgcn_mfma_f32_16x16x32_bf16(b.ak[jsub][0], bq[isub][0], s, 0, 0, 0);
                s = __builtin_amdgcn_mfma_f32_16x16x32_bf16(b.ak[jsub][1], bq[isub][1], s, 0, 0, 0);
                int i = iw + isub * 16 + lr;
                int jb0 = wnd * 32 + jsub * 16 + lg * 4;
                float p[4];
#pragma unroll
                for (int rg = 0; rg < 4; rg++)
                    p[rg] = (jb0 + rg <= i) ? __expf(s[rg]) : 0.0f;
                pk[jsub][isub][0] = cvt_pk_bf16(p[0], p[1]);
                pk[jsub][isub][1] = cvt_pk_bf16(p[2], p[3]);
            }
        __builtin_amdgcn_s_setprio(1);
#pragma unroll
        for (int isub = 0; isub < 2; isub++) {
            int a0 = __shfl((int)pk[0][isub][0], src0);
            int a1 = __shfl((int)pk[0][isub][1], src0);
            int a2 = __shfl((int)pk[0][isub][0], src1);
            int a3 = __shfl((int)pk[0][isub][1], src1);
            int b0 = __shfl((int)pk[1][isub][0], src0);
            int b1 = __shfl((int)pk[1][isub][1], src0);
            int b2 = __shfl((int)pk[1][isub][0], src1);
            int b3 = __shfl((int)pk[1][isub][1], src1);
            int4 wv;
            wv.x = jlow ? a0 : b0;
            wv.y = jlow ? a1 : b1;
            wv.z = jlow ? a2 : b2;
            wv.w = jlow ? a3 : b3;
            short8v bp = __builtin_bit_cast(short8v, wv);
#pragma unroll
            for (int csub = 0; csub < 4; csub++)
                acc[csub][isub] = __builtin_amdgcn_mfma_f32_16x16x32_bf16(b.av[csub], bp, acc[csub][isub], 0, 0, 0);
        }
        __builtin_amdgcn_s_setprio(0);
    };

    WBuf A, B;
    loadWin(0, A);
    int wnd = 0;
    for (; wnd + 1 <= tile; wnd += 2) {
        loadWin(wnd + 1, B);
        computeWin(wnd, A);
        int n2 = (wnd + 2 <= tile) ? wnd + 2 : wnd + 1;
        loadWin(n2, A);
        computeWin(wnd + 1, B);
    }
    if (wnd <= tile) computeWin(wnd, A);

#pragma unroll
    for (int csub = 0; csub < 4; csub++)
#pragma unroll
        for (int isub = 0; isub < 2; isub++) {
            int i = iw + isub * 16 + lr;
            int c0 = csub * 16 + lg * 4;
            unsigned short t4[4];
#pragma unroll
            for (int rg = 0; rg < 4; rg++) t4[rg] = f2bf(acc[csub][isub][rg]);
            *(uint2*)&Ch[(size_t)i * HDIM + c0] = *(uint2*)t4;
        }
}

// ---------------------------------------------------------------------------
extern "C" void kernel_launch(void* const* d_in, const int* in_sizes, int n_in,
                              void* d_out, int out_size, void* d_ws, size_t ws_size,
                              hipStream_t stream)
{
    const float* H_q = (const float*)d_in[0];
    const float* H_k = (const float*)d_in[1];
    const float* H_v = (const float*)d_in[2];
    const float* W_q = (const float*)d_in[3];
    const float* b_q = (const float*)d_in[4];
    const float* W_k = (const float*)d_in[5];
    const float* b_k = (const float*)d_in[6];
    const float* W_v = (const float*)d_in[7];
    const float* b_v = (const float*)d_in[8];
    const float* W_o = (const float*)d_in[9];
    const float* b_o = (const float*)d_in[10];

    char* ws = (char*)d_ws;
    const size_t MB = (size_t)1 << 20;
    const float scale = 0.03125f;  // 1/sqrt(1024)

    if (ws_size >= 60 * MB) {
        unsigned short* Hbf = (unsigned short*)(ws);
        unsigned short* Vt  = (unsigned short*)(ws);
        unsigned short* Ctx = (unsigned short*)(ws + 8 * MB);
        unsigned short* Wt4 = (unsigned short*)(ws + 24 * MB);
        unsigned short* Qb  = (unsigned short*)(ws + 32 * MB);
        unsigned short* Kb  = (unsigned short*)(ws + 40 * MB);
        unsigned short* Vb  = (unsigned short*)(ws + 48 * MB);
        float* rcpC = (float*)(ws + 56 * MB);

        wtrans_kernel<<<dim3(16, 16, 4), 256, 0, stream>>>(W_q, W_k, W_v, W_o, Wt4);
        hconv_kernel<<<dim3(2048, 3), 256, 0, stream>>>(H_q, H_k, H_v, Hbf);
        gemm_glds_kernel<false><<<dim3(24, 32), 256, 0, stream>>>(
            Hbf, Wt4, b_q, b_k, b_v, scale, 1.0f, Qb);
        colsum_kernel<<<1024, 256, 0, stream>>>(Qb, Kb, rcpC);
        vtrans_kernel<<<dim3(32, 32), 256, 0, stream>>>(Vb, rcpC, Vt);
        attn_kernel<<<2048, 64, 0, stream>>>(Qb, Kb, Vt, Ctx);
        gemm_glds_kernel<true><<<dim3(8, 32), 256, 0, stream>>>(
            Ctx, Wt4 + (size_t)3 * 1024 * 1024, b_o, b_o, b_o, 1.0f, 1.0f, d_out);
    } else {
        unsigned short* Qb  = (unsigned short*)(ws + 0 * MB);
        unsigned short* Kb  = (unsigned short*)(ws + 8 * MB);
        unsigned short* Vt  = (unsigned short*)(ws + 16 * MB);
        unsigned short* Vb  = (unsigned short*)(ws + 24 * MB);
        unsigned short* Ctx = (unsigned short*)(ws + 24 * MB);
        unsigned short* Wt4 = (unsigned short*)(ws + 32 * MB);
        float* rcpC = (float*)(ws + 40 * MB);

        wtrans_kernel<<<dim3(16, 16, 4), 256, 0, stream>>>(W_q, W_k, W_v, W_o, Wt4);
        gemm_bt_kernel<false, true><<<dim3(8, 32), 256, 0, stream>>>(H_q, Wt4, b_q, scale, Qb);
        gemm_bt_kernel<false, true><<<dim3(8, 32), 256, 0, stream>>>(H_k, Wt4 + (size_t)1024 * 1024, b_k, scale, Kb);
        gemm_bt_kernel<false, true><<<dim3(8, 32), 256, 0, stream>>>(H_v, Wt4 + (size_t)2 * 1024 * 1024, b_v, 1.0f, Vb);
        colsum_kernel<<<1024, 256, 0, stream>>>(Qb, Kb, rcpC);
        vtrans_kernel<<<dim3(32, 32), 256, 0, stream>>>(Vb, rcpC, Vt);
        attn_kernel<<<2048, 64, 0, stream>>>(Qb, Kb, Vt, Ctx);
        gemm_bt_kernel<true, false><<<dim3(8, 32), 256, 0, stream>>>(Ctx, Wt4 + (size_t)3 * 1024 * 1024, b_o, 1.0f, d_out);
    }
}

// Round 5
// 224.408 us; speedup vs baseline: 1.4454x; 1.0004x over previous
//
#include <hip/hip_runtime.h>

#define L 2048
#define HSZ 1024
#define HDIM 64
// 32 head-panels total (N=2 batches x 16 heads), each a contiguous [2048][64]

typedef float f32x4 __attribute__((ext_vector_type(4)));
typedef short short8v __attribute__((ext_vector_type(8)));

static __device__ __forceinline__ unsigned short f2bf(float f) {
    unsigned int u = __builtin_bit_cast(unsigned int, f);
    u += 0x7FFFu + ((u >> 16) & 1u);   // RNE
    return (unsigned short)(u >> 16);
}
static __device__ __forceinline__ float bf2f(unsigned short u) {
    return __builtin_bit_cast(float, (unsigned int)u << 16);
}
static __device__ __forceinline__ unsigned int cvt_pk_bf16(float lo, float hi) {
    unsigned int r;
    asm("v_cvt_pk_bf16_f32 %0, %1, %2" : "=v"(r) : "v"(lo), "v"(hi));
    return r;
}
static __device__ __forceinline__ void gload_lds16(const void* g, void* l) {
    __builtin_amdgcn_global_load_lds(
        (const __attribute__((address_space(1))) unsigned int*)g,
        (__attribute__((address_space(3))) unsigned int*)l, 16, 0, 0);
}

// ---------------------------------------------------------------------------
// Weights: Wt4[z][n][k] = bf16(W_z[k][n]) for z in {q,k,v,o}.
// ---------------------------------------------------------------------------
__global__ __launch_bounds__(256) void wtrans_kernel(
    const float* __restrict__ W0, const float* __restrict__ W1,
    const float* __restrict__ W2, const float* __restrict__ W3,
    unsigned short* __restrict__ Wt4)
{
    const float* W;
    int z = blockIdx.z;
    if (z == 0) W = W0; else if (z == 1) W = W1; else if (z == 2) W = W2; else W = W3;
    unsigned short* T = Wt4 + (size_t)z * HSZ * HSZ;

    __shared__ __align__(16) unsigned short tl[64][72];
    int t = threadIdx.x;
    int k0 = blockIdx.y * 64, n0 = blockIdx.x * 64;

    int kl = t >> 2, nc = (t & 3) * 16;
    const float* src = W + (size_t)(k0 + kl) * HSZ + n0 + nc;
#pragma unroll
    for (int q = 0; q < 4; q++) {
        float4 v = ((const float4*)src)[q];
        tl[kl][nc + q * 4 + 0] = f2bf(v.x);
        tl[kl][nc + q * 4 + 1] = f2bf(v.y);
        tl[kl][nc + q * 4 + 2] = f2bf(v.z);
        tl[kl][nc + q * 4 + 3] = f2bf(v.w);
    }
    __syncthreads();
    int nl = t >> 2, kc = (t & 3) * 16;
    unsigned short tmp[16];
#pragma unroll
    for (int e = 0; e < 16; e++) tmp[e] = tl[kc + e][nl];
    unsigned short* dst = T + (size_t)(n0 + nl) * HSZ + k0 + kc;
    ((uint4*)dst)[0] = *(uint4*)&tmp[0];
    ((uint4*)dst)[1] = *(uint4*)&tmp[8];
}

// ---------------------------------------------------------------------------
// Convert H_q/H_k/H_v fp32 -> bf16 into contiguous Hbf[3][4096][1024].
// ---------------------------------------------------------------------------
__global__ __launch_bounds__(256) void hconv_kernel(
    const float* __restrict__ H0, const float* __restrict__ H1,
    const float* __restrict__ H2, unsigned short* __restrict__ Hbf)
{
    int z = blockIdx.y;
    const float* S = (z == 0) ? H0 : (z == 1) ? H1 : H2;
    size_t base = ((size_t)blockIdx.x * 256 + threadIdx.x) * 8;
    unsigned short* D = Hbf + (size_t)z * (4096 * 1024) + base;
    float4 a = *(const float4*)(S + base);
    float4 b = *(const float4*)(S + base + 4);
    unsigned short o[8] = {f2bf(a.x), f2bf(a.y), f2bf(a.z), f2bf(a.w),
                           f2bf(b.x), f2bf(b.y), f2bf(b.z), f2bf(b.w)};
    *(uint4*)D = *(const uint4*)o;
}

// ---------------------------------------------------------------------------
// m97-style GEMM: out[proj][4096][1024] = A[proj] @ B[proj]^T + bias, *scale.
// ---------------------------------------------------------------------------
template<bool OUTF32>
__global__ __launch_bounds__(256) void gemm_glds_kernel(
    const unsigned short* __restrict__ A, const unsigned short* __restrict__ B,
    const float* __restrict__ bias0, const float* __restrict__ bias1,
    const float* __restrict__ bias2, float scale01, float scale2,
    void* __restrict__ outbase)
{
    __shared__ __align__(16) unsigned short As[128 * 32];
    __shared__ __align__(16) unsigned short Bs[128 * 32];

    int t = threadIdx.x;
    int lane = t & 63, w = t >> 6;
    int lr = lane & 15, lg = lane >> 4;
    int proj = blockIdx.x >> 3;
    int nb = (blockIdx.x & 7) * 128;
    int mb = blockIdx.y * 128;
    int wm = (w >> 1) * 64, wn = (w & 1) * 64;

    const unsigned short* Ap = A + (size_t)proj * (4096 * 1024);
    const unsigned short* Bp = B + (size_t)proj * (1024 * 1024);
    const float* bias = (proj == 0) ? bias0 : (proj == 1) ? bias1 : bias2;
    float scale = (proj < 2) ? scale01 : scale2;

    int c0 = w * 64 + lane;
    int r0 = c0 >> 2, e0 = (c0 & 3) * 8;
    int r1 = r0 + 64;
    const unsigned short* gA0 = Ap + (size_t)(mb + r0) * HSZ + e0;
    const unsigned short* gA1 = Ap + (size_t)(mb + r1) * HSZ + e0;
    const unsigned short* gB0 = Bp + (size_t)(nb + r0) * HSZ + e0;
    const unsigned short* gB1 = Bp + (size_t)(nb + r1) * HSZ + e0;
    unsigned short* lA0 = As + w * 512;
    unsigned short* lA1 = As + 2048 + w * 512;
    unsigned short* lB0 = Bs + w * 512;
    unsigned short* lB1 = Bs + 2048 + w * 512;

    f32x4 acc[4][4] = {};

    for (int kt = 0; kt < HSZ; kt += 32) {
        gload_lds16(gA0 + kt, lA0);
        gload_lds16(gA1 + kt, lA1);
        gload_lds16(gB0 + kt, lB0);
        gload_lds16(gB1 + kt, lB1);
        __syncthreads();

        short8v af[4], bfv[4];
#pragma unroll
        for (int s = 0; s < 4; s++) {
            af[s]  = *(const short8v*)&As[(wm + s * 16 + lr) * 32 + lg * 8];
            bfv[s] = *(const short8v*)&Bs[(wn + s * 16 + lr) * 32 + lg * 8];
        }
#pragma unroll
        for (int i = 0; i < 4; i++)
#pragma unroll
            for (int j = 0; j < 4; j++)
                acc[i][j] = __builtin_amdgcn_mfma_f32_16x16x32_bf16(af[i], bfv[j], acc[i][j], 0, 0, 0);
        __syncthreads();
    }

#pragma unroll
    for (int j = 0; j < 4; j++) {
        int col = nb + wn + j * 16 + lr;
        float bv = bias[col];
#pragma unroll
        for (int i = 0; i < 4; i++) {
            int row0 = mb + wm + i * 16 + lg * 4;
#pragma unroll
            for (int rg = 0; rg < 4; rg++) {
                float v = (acc[i][j][rg] + bv) * scale;
                if (OUTF32)
                    ((float*)outbase)[(size_t)(row0 + rg) * HSZ + col] = v;
                else
                    ((unsigned short*)outbase)[(size_t)proj * (4096 * 1024) +
                                               (size_t)(row0 + rg) * HSZ + col] = f2bf(v);
            }
        }
    }
}

// ---------------------------------------------------------------------------
// Legacy fp32-A GEMM (fallback path if ws is small).
// ---------------------------------------------------------------------------
template<bool ABF16, bool OUTBF16>
__global__ __launch_bounds__(256) void gemm_bt_kernel(
    const void* __restrict__ Aptr, const unsigned short* __restrict__ Bt,
    const float* __restrict__ bias, float scale, void* __restrict__ outp)
{
    __shared__ __align__(16) unsigned short As[128][40];
    __shared__ __align__(16) unsigned short Bs[128][40];

    int t = threadIdx.x;
    int lane = t & 63, w = t >> 6;
    int lr = lane & 15, lg = lane >> 4;
    int mb = blockIdx.y * 128, nb = blockIdx.x * 128;
    int wm = (w >> 1) * 64, wn = (w & 1) * 64;
    int r = t >> 1, cc = (t & 1) * 16;

    f32x4 acc[4][4] = {};

    for (int kt = 0; kt < HSZ; kt += 32) {
        if (ABF16) {
            const unsigned short* A = (const unsigned short*)Aptr + (size_t)(mb + r) * HSZ + kt + cc;
            *(uint4*)&As[r][cc]     = ((const uint4*)A)[0];
            *(uint4*)&As[r][cc + 8] = ((const uint4*)A)[1];
        } else {
            const float* A = (const float*)Aptr + (size_t)(mb + r) * HSZ + kt + cc;
            unsigned short tmp[16];
#pragma unroll
            for (int q = 0; q < 4; q++) {
                float4 v = ((const float4*)A)[q];
                tmp[q * 4 + 0] = f2bf(v.x); tmp[q * 4 + 1] = f2bf(v.y);
                tmp[q * 4 + 2] = f2bf(v.z); tmp[q * 4 + 3] = f2bf(v.w);
            }
            *(uint4*)&As[r][cc]     = *(uint4*)&tmp[0];
            *(uint4*)&As[r][cc + 8] = *(uint4*)&tmp[8];
        }
        {
            const unsigned short* B = Bt + (size_t)(nb + r) * HSZ + kt + cc;
            *(uint4*)&Bs[r][cc]     = ((const uint4*)B)[0];
            *(uint4*)&Bs[r][cc + 8] = ((const uint4*)B)[1];
        }
        __syncthreads();

        short8v af[4], bf[4];
#pragma unroll
        for (int s = 0; s < 4; s++) af[s] = *(const short8v*)&As[wm + s * 16 + lr][8 * lg];
#pragma unroll
        for (int s = 0; s < 4; s++) bf[s] = *(const short8v*)&Bs[wn + s * 16 + lr][8 * lg];
#pragma unroll
        for (int i = 0; i < 4; i++)
#pragma unroll
            for (int j = 0; j < 4; j++)
                acc[i][j] = __builtin_amdgcn_mfma_f32_16x16x32_bf16(af[i], bf[j], acc[i][j], 0, 0, 0);
        __syncthreads();
    }

#pragma unroll
    for (int j = 0; j < 4; j++) {
        int col = nb + wn + j * 16 + lr;
        float bv = bias[col];
#pragma unroll
        for (int i = 0; i < 4; i++) {
            int row0 = mb + wm + i * 16 + lg * 4;
#pragma unroll
            for (int rg = 0; rg < 4; rg++) {
                float v = (acc[i][j][rg] + bv) * scale;
                if (OUTBF16)
                    ((unsigned short*)outp)[(size_t)(row0 + rg) * HSZ + col] = f2bf(v);
                else
                    ((float*)outp)[(size_t)(row0 + rg) * HSZ + col] = v;
            }
        }
    }
}

// ---------------------------------------------------------------------------
// Phase 1: rcpC[head][j] = 1 / sum_{i>=j} exp(S_ij). S^T = mfma(K,Q).
// 1D grid with XCD remap: 4 heads per XCD (K/Q panels L2-resident).
// ---------------------------------------------------------------------------
__global__ __launch_bounds__(256) void colsum_kernel(
    const unsigned short* __restrict__ Qb, const unsigned short* __restrict__ Kb,
    float* __restrict__ rcpC)
{
    int raw = blockIdx.x;
    int xcd = raw & 7, idx = raw >> 3;        // idx in [0,128)
    int head = xcd * 4 + (idx >> 5);          // 4 heads per XCD
    int jb = (idx & 31) * 64;
    const unsigned short* Qh = Qb + (size_t)head * L * HDIM;
    const unsigned short* Kh = Kb + (size_t)head * L * HDIM;
    int t = threadIdx.x, lane = t & 63, w = t >> 6;
    int lr = lane & 15, lg = lane >> 4;

    short8v af[4][2];
#pragma unroll
    for (int sj = 0; sj < 4; sj++)
#pragma unroll
        for (int kk = 0; kk < 2; kk++)
            af[sj][kk] = *(const short8v*)&Kh[(size_t)(jb + sj * 16 + lr) * HDIM + kk * 32 + 8 * lg];

    float accs[4][4] = {};

    int it0 = jb + w * 16;
    short8v bc0 = *(const short8v*)&Qh[(size_t)(it0 + lr) * HDIM + 8 * lg];
    short8v bc1 = *(const short8v*)&Qh[(size_t)(it0 + lr) * HDIM + 32 + 8 * lg];

    for (int it = it0; it < L; it += 64) {
        int itn = (it + 64 < L) ? it + 64 : it;
        short8v bn0 = *(const short8v*)&Qh[(size_t)(itn + lr) * HDIM + 8 * lg];
        short8v bn1 = *(const short8v*)&Qh[(size_t)(itn + lr) * HDIM + 32 + 8 * lg];
        int i = it + lr;
#pragma unroll
        for (int sj = 0; sj < 4; sj++) {
            f32x4 d = {0.0f, 0.0f, 0.0f, 0.0f};
            d = __builtin_amdgcn_mfma_f32_16x16x32_bf16(af[sj][0], bc0, d, 0, 0, 0);
            d = __builtin_amdgcn_mfma_f32_16x16x32_bf16(af[sj][1], bc1, d, 0, 0, 0);
#pragma unroll
            for (int rg = 0; rg < 4; rg++) {
                int j = jb + sj * 16 + lg * 4 + rg;
                if (i >= j) accs[sj][rg] += __expf(d[rg]);
            }
        }
        bc0 = bn0; bc1 = bn1;
    }

    __shared__ float part[4][64];
#pragma unroll
    for (int sj = 0; sj < 4; sj++)
#pragma unroll
        for (int rg = 0; rg < 4; rg++) {
            float v = accs[sj][rg];
            v += __shfl_xor(v, 1); v += __shfl_xor(v, 2);
            v += __shfl_xor(v, 4); v += __shfl_xor(v, 8);
            if (lr == 0) part[w][sj * 16 + lg * 4 + rg] = v;
        }
    __syncthreads();
    if (t < 64) {
        float s = part[0][t] + part[1][t] + part[2][t] + part[3][t];
        rcpC[(size_t)head * L + jb + t] = 1.0f / s;
    }
}

// ---------------------------------------------------------------------------
// V transpose with rcpC folded: Vt[p][c][j] = bf16(V[p][j][c] * rcpC[p][j]).
// ---------------------------------------------------------------------------
__global__ __launch_bounds__(256) void vtrans_kernel(
    const unsigned short* __restrict__ Vb, const float* __restrict__ rcpC,
    unsigned short* __restrict__ Vt)
{
    int p = blockIdx.y;
    int j0 = blockIdx.x * 64;
    const unsigned short* Vp = Vb + (size_t)p * L * HDIM;
    unsigned short* Tp = Vt + (size_t)p * HDIM * L;
    __shared__ __align__(16) unsigned short tl[64][72];
    int t = threadIdx.x;
    int jl = t >> 2, c0 = (t & 3) * 16;
    float rcv = rcpC[(size_t)p * L + j0 + jl];
    const unsigned short* src = Vp + (size_t)(j0 + jl) * HDIM + c0;
    unsigned short raw[16];
    *(uint4*)&raw[0] = ((const uint4*)src)[0];
    *(uint4*)&raw[8] = ((const uint4*)src)[1];
#pragma unroll
    for (int e = 0; e < 16; e++) tl[jl][c0 + e] = f2bf(bf2f(raw[e]) * rcv);
    __syncthreads();
    int cl = t >> 2, jc = (t & 3) * 16;
    unsigned short tmp[16];
#pragma unroll
    for (int e = 0; e < 16; e++) tmp[e] = tl[jc + e][cl];
    unsigned short* dst = Tp + (size_t)cl * L + j0 + jc;
    ((uint4*)dst)[0] = *(uint4*)&tmp[0];
    ((uint4*)dst)[1] = *(uint4*)&tmp[8];
}

// ---------------------------------------------------------------------------
// Phase 2: 4-wave blocks; wave w handles windows w, w+4, ... of its i-tile
// (exact split: ctx is a plain sum, denom pre-folded into Vt). End: LDS
// reduction across the 4 waves, one barrier. XCD remap pins 4 heads/XCD;
// snake pairing (big+small tiles adjacent) balances per-CU work.
// ---------------------------------------------------------------------------
struct WBuf { short8v ak[2][2]; short8v av[4]; };

__global__ __launch_bounds__(256) void attn_kernel(
    const unsigned short* __restrict__ Qb, const unsigned short* __restrict__ Kb,
    const unsigned short* __restrict__ Vt, unsigned short* __restrict__ Ctx)
{
    int raw = blockIdx.x;
    int xcd = raw & 7, idx = raw >> 3;        // idx in [0,256)
    int head = xcd * 4 + (idx >> 6);          // 4 heads per XCD
    int j = idx & 63;
    int tile = (j & 1) ? (j >> 1) : (63 - (j >> 1));   // snake: balanced pairs
    int iw = tile * 32;
    const unsigned short* Qh = Qb + (size_t)head * L * HDIM;
    const unsigned short* Kh = Kb + (size_t)head * L * HDIM;
    const unsigned short* Vh = Vt + (size_t)head * HDIM * L;   // [64][2048]
    unsigned short* Ch = Ctx + (size_t)head * L * HDIM;

    int t = threadIdx.x;
    int lane = t & 63, wv = t >> 6;
    int lr = lane & 15, lg = lane >> 4;
    int src0 = ((lane & 16) << 1) + lr;
    int src1 = src0 + 16;
    bool jlow = (lg < 2);

    short8v bq[2][2];
#pragma unroll
    for (int isub = 0; isub < 2; isub++)
#pragma unroll
        for (int kd = 0; kd < 2; kd++)
            bq[isub][kd] = *(const short8v*)&Qh[(size_t)(iw + isub * 16 + lr) * HDIM + kd * 32 + 8 * lg];

    f32x4 acc[4][2] = {};

    auto loadWin = [&](int w2, WBuf& b) {
        int jt = w2 * 32;
#pragma unroll
        for (int jsub = 0; jsub < 2; jsub++)
#pragma unroll
            for (int kd = 0; kd < 2; kd++)
                b.ak[jsub][kd] = *(const short8v*)&Kh[(size_t)(jt + jsub * 16 + lr) * HDIM + kd * 32 + 8 * lg];
#pragma unroll
        for (int csub = 0; csub < 4; csub++)
            b.av[csub] = *(const short8v*)&Vh[(size_t)(csub * 16 + lr) * L + jt + 8 * lg];
    };

    auto computeWin = [&](int wnd, const WBuf& b) {
        unsigned int pk[2][2][2];
#pragma unroll
        for (int jsub = 0; jsub < 2; jsub++)
#pragma unroll
            for (int isub = 0; isub < 2; isub++) {
                f32x4 s = {0.0f, 0.0f, 0.0f, 0.0f};
                s = __builtin_amdgcn_mfma_f32_16x16x32_bf16(b.ak[jsub][0], bq[isub][0], s, 0, 0, 0);
                s = __builtin_amdgcn_mfma_f32_16x16x32_bf16(b.ak[jsub][1], bq[isub][1], s, 0, 0, 0);
                int i = iw + isub * 16 + lr;
                int jb0 = wnd * 32 + jsub * 16 + lg * 4;
                float p[4];
#pragma unroll
                for (int rg = 0; rg < 4; rg++)
                    p[rg] = (jb0 + rg <= i) ? __expf(s[rg]) : 0.0f;
                pk[jsub][isub][0] = cvt_pk_bf16(p[0], p[1]);
                pk[jsub][isub][1] = cvt_pk_bf16(p[2], p[3]);
            }
        __builtin_amdgcn_s_setprio(1);
#pragma unroll
        for (int isub = 0; isub < 2; isub++) {
            int a0 = __shfl((int)pk[0][isub][0], src0);
            int a1 = __shfl((int)pk[0][isub][1], src0);
            int a2 = __shfl((int)pk[0][isub][0], src1);
            int a3 = __shfl((int)pk[0][isub][1], src1);
            int b0 = __shfl((int)pk[1][isub][0], src0);
            int b1 = __shfl((int)pk[1][isub][1], src0);
            int b2 = __shfl((int)pk[1][isub][0], src1);
            int b3 = __shfl((int)pk[1][isub][1], src1);
            int4 wvv;
            wvv.x = jlow ? a0 : b0;
            wvv.y = jlow ? a1 : b1;
            wvv.z = jlow ? a2 : b2;
            wvv.w = jlow ? a3 : b3;
            short8v bp = __builtin_bit_cast(short8v, wvv);
#pragma unroll
            for (int csub = 0; csub < 4; csub++)
                acc[csub][isub] = __builtin_amdgcn_mfma_f32_16x16x32_bf16(b.av[csub], bp, acc[csub][isub], 0, 0, 0);
        }
        __builtin_amdgcn_s_setprio(0);
    };

    // wave wv: windows wv, wv+4, wv+8, ... (<= tile), ping-pong prefetch
    WBuf A, B;
    int wnd = wv;
    if (wnd <= tile) loadWin(wnd, A);
    for (; wnd + 4 <= tile; wnd += 8) {
        loadWin(wnd + 4, B);
        computeWin(wnd, A);
        int n2 = (wnd + 8 <= tile) ? wnd + 8 : wnd + 4;
        loadWin(n2, A);
        computeWin(wnd + 4, B);
    }
    if (wnd <= tile) computeWin(wnd, A);

    // cross-wave reduction: waves 1-3 dump partial ctx, wave 0 sums + stores
    __shared__ __align__(16) float red[3][64][36];
    if (wv > 0) {
#pragma unroll
        for (int csub = 0; csub < 4; csub++)
#pragma unroll
            for (int isub = 0; isub < 2; isub++)
                *(f32x4*)&red[wv - 1][lane][csub * 8 + isub * 4] = acc[csub][isub];
    }
    __syncthreads();
    if (wv == 0) {
#pragma unroll
        for (int u = 0; u < 3; u++)
#pragma unroll
            for (int csub = 0; csub < 4; csub++)
#pragma unroll
                for (int isub = 0; isub < 2; isub++)
                    acc[csub][isub] += *(const f32x4*)&red[u][lane][csub * 8 + isub * 4];

#pragma unroll
        for (int csub = 0; csub < 4; csub++)
#pragma unroll
            for (int isub = 0; isub < 2; isub++) {
                int i = iw + isub * 16 + lr;
                int c0 = csub * 16 + lg * 4;
                unsigned short t4[4];
#pragma unroll
                for (int rg = 0; rg < 4; rg++) t4[rg] = f2bf(acc[csub][isub][rg]);
                *(uint2*)&Ch[(size_t)i * HDIM + c0] = *(uint2*)t4;
            }
    }
}

// ---------------------------------------------------------------------------
extern "C" void kernel_launch(void* const* d_in, const int* in_sizes, int n_in,
                              void* d_out, int out_size, void* d_ws, size_t ws_size,
                              hipStream_t stream)
{
    const float* H_q = (const float*)d_in[0];
    const float* H_k = (const float*)d_in[1];
    const float* H_v = (const float*)d_in[2];
    const float* W_q = (const float*)d_in[3];
    const float* b_q = (const float*)d_in[4];
    const float* W_k = (const float*)d_in[5];
    const float* b_k = (const float*)d_in[6];
    const float* W_v = (const float*)d_in[7];
    const float* b_v = (const float*)d_in[8];
    const float* W_o = (const float*)d_in[9];
    const float* b_o = (const float*)d_in[10];

    char* ws = (char*)d_ws;
    const size_t MB = (size_t)1 << 20;
    const float scale = 0.03125f;  // 1/sqrt(1024)

    if (ws_size >= 60 * MB) {
        unsigned short* Hbf = (unsigned short*)(ws);
        unsigned short* Vt  = (unsigned short*)(ws);
        unsigned short* Ctx = (unsigned short*)(ws + 8 * MB);
        unsigned short* Wt4 = (unsigned short*)(ws + 24 * MB);
        unsigned short* Qb  = (unsigned short*)(ws + 32 * MB);
        unsigned short* Kb  = (unsigned short*)(ws + 40 * MB);
        unsigned short* Vb  = (unsigned short*)(ws + 48 * MB);
        float* rcpC = (float*)(ws + 56 * MB);

        wtrans_kernel<<<dim3(16, 16, 4), 256, 0, stream>>>(W_q, W_k, W_v, W_o, Wt4);
        hconv_kernel<<<dim3(2048, 3), 256, 0, stream>>>(H_q, H_k, H_v, Hbf);
        gemm_glds_kernel<false><<<dim3(24, 32), 256, 0, stream>>>(
            Hbf, Wt4, b_q, b_k, b_v, scale, 1.0f, Qb);
        colsum_kernel<<<1024, 256, 0, stream>>>(Qb, Kb, rcpC);
        vtrans_kernel<<<dim3(32, 32), 256, 0, stream>>>(Vb, rcpC, Vt);
        attn_kernel<<<2048, 256, 0, stream>>>(Qb, Kb, Vt, Ctx);
        gemm_glds_kernel<true><<<dim3(8, 32), 256, 0, stream>>>(
            Ctx, Wt4 + (size_t)3 * 1024 * 1024, b_o, b_o, b_o, 1.0f, 1.0f, d_out);
    } else {
        unsigned short* Qb  = (unsigned short*)(ws + 0 * MB);
        unsigned short* Kb  = (unsigned short*)(ws + 8 * MB);
        unsigned short* Vt  = (unsigned short*)(ws + 16 * MB);
        unsigned short* Vb  = (unsigned short*)(ws + 24 * MB);
        unsigned short* Ctx = (unsigned short*)(ws + 24 * MB);
        unsigned short* Wt4 = (unsigned short*)(ws + 32 * MB);
        float* rcpC = (float*)(ws + 40 * MB);

        wtrans_kernel<<<dim3(16, 16, 4), 256, 0, stream>>>(W_q, W_k, W_v, W_o, Wt4);
        gemm_bt_kernel<false, true><<<dim3(8, 32), 256, 0, stream>>>(H_q, Wt4, b_q, scale, Qb);
        gemm_bt_kernel<false, true><<<dim3(8, 32), 256, 0, stream>>>(H_k, Wt4 + (size_t)1024 * 1024, b_k, scale, Kb);
        gemm_bt_kernel<false, true><<<dim3(8, 32), 256, 0, stream>>>(H_v, Wt4 + (size_t)2 * 1024 * 1024, b_v, 1.0f, Vb);
        colsum_kernel<<<1024, 256, 0, stream>>>(Qb, Kb, rcpC);
        vtrans_kernel<<<dim3(32, 32), 256, 0, stream>>>(Vb, rcpC, Vt);
        attn_kernel<<<2048, 256, 0, stream>>>(Qb, Kb, Vt, Ctx);
        gemm_bt_kernel<true, false><<<dim3(8, 32), 256, 0, stream>>>(Ctx, Wt4 + (size_t)3 * 1024 * 1024, b_o, 1.0f, d_out);
    }
}

// Round 6
// 187.917 us; speedup vs baseline: 1.7260x; 1.1942x over previous
//
#include <hip/hip_runtime.h>

#define L 2048
#define HSZ 1024
#define HDIM 64
// 32 head-panels total (N=2 batches x 16 heads), each a contiguous [2048][64]

typedef float f32x4 __attribute__((ext_vector_type(4)));
typedef short short8v __attribute__((ext_vector_type(8)));

static __device__ __forceinline__ unsigned short f2bf(float f) {
    unsigned int u = __builtin_bit_cast(unsigned int, f);
    u += 0x7FFFu + ((u >> 16) & 1u);   // RNE
    return (unsigned short)(u >> 16);
}
static __device__ __forceinline__ float bf2f(unsigned short u) {
    return __builtin_bit_cast(float, (unsigned int)u << 16);
}
static __device__ __forceinline__ unsigned int cvt_pk_bf16(float lo, float hi) {
    unsigned int r;
    asm("v_cvt_pk_bf16_f32 %0, %1, %2" : "=v"(r) : "v"(lo), "v"(hi));
    return r;
}
static __device__ __forceinline__ void gload_lds16(const void* g, void* l) {
    __builtin_amdgcn_global_load_lds(
        (const __attribute__((address_space(1))) unsigned int*)g,
        (__attribute__((address_space(3))) unsigned int*)l, 16, 0, 0);
}

// ---------------------------------------------------------------------------
// Weights: Wt4[z][n][k] = bf16(W_z[k][n]) for z in {q,k,v,o}.
// ---------------------------------------------------------------------------
__global__ __launch_bounds__(256) void wtrans_kernel(
    const float* __restrict__ W0, const float* __restrict__ W1,
    const float* __restrict__ W2, const float* __restrict__ W3,
    unsigned short* __restrict__ Wt4)
{
    const float* W;
    int z = blockIdx.z;
    if (z == 0) W = W0; else if (z == 1) W = W1; else if (z == 2) W = W2; else W = W3;
    unsigned short* T = Wt4 + (size_t)z * HSZ * HSZ;

    __shared__ __align__(16) unsigned short tl[64][72];
    int t = threadIdx.x;
    int k0 = blockIdx.y * 64, n0 = blockIdx.x * 64;

    int kl = t >> 2, nc = (t & 3) * 16;
    const float* src = W + (size_t)(k0 + kl) * HSZ + n0 + nc;
#pragma unroll
    for (int q = 0; q < 4; q++) {
        float4 v = ((const float4*)src)[q];
        tl[kl][nc + q * 4 + 0] = f2bf(v.x);
        tl[kl][nc + q * 4 + 1] = f2bf(v.y);
        tl[kl][nc + q * 4 + 2] = f2bf(v.z);
        tl[kl][nc + q * 4 + 3] = f2bf(v.w);
    }
    __syncthreads();
    int nl = t >> 2, kc = (t & 3) * 16;
    unsigned short tmp[16];
#pragma unroll
    for (int e = 0; e < 16; e++) tmp[e] = tl[kc + e][nl];
    unsigned short* dst = T + (size_t)(n0 + nl) * HSZ + k0 + kc;
    ((uint4*)dst)[0] = *(uint4*)&tmp[0];
    ((uint4*)dst)[1] = *(uint4*)&tmp[8];
}

// ---------------------------------------------------------------------------
// Convert H_q/H_k/H_v fp32 -> bf16 into contiguous Hbf[3][4096][1024].
// ---------------------------------------------------------------------------
__global__ __launch_bounds__(256) void hconv_kernel(
    const float* __restrict__ H0, const float* __restrict__ H1,
    const float* __restrict__ H2, unsigned short* __restrict__ Hbf)
{
    int z = blockIdx.y;
    const float* S = (z == 0) ? H0 : (z == 1) ? H1 : H2;
    size_t base = ((size_t)blockIdx.x * 256 + threadIdx.x) * 8;
    unsigned short* D = Hbf + (size_t)z * (4096 * 1024) + base;
    float4 a = *(const float4*)(S + base);
    float4 b = *(const float4*)(S + base + 4);
    unsigned short o[8] = {f2bf(a.x), f2bf(a.y), f2bf(a.z), f2bf(a.w),
                           f2bf(b.x), f2bf(b.y), f2bf(b.z), f2bf(b.w)};
    *(uint4*)D = *(const uint4*)o;
}

// ---------------------------------------------------------------------------
// m97-style GEMM: out[proj][4096][1024] = A[proj] @ B[proj]^T + bias, *scale.
// ---------------------------------------------------------------------------
template<bool OUTF32>
__global__ __launch_bounds__(256) void gemm_glds_kernel(
    const unsigned short* __restrict__ A, const unsigned short* __restrict__ B,
    const float* __restrict__ bias0, const float* __restrict__ bias1,
    const float* __restrict__ bias2, float scale01, float scale2,
    void* __restrict__ outbase)
{
    __shared__ __align__(16) unsigned short As[128 * 32];
    __shared__ __align__(16) unsigned short Bs[128 * 32];

    int t = threadIdx.x;
    int lane = t & 63, w = t >> 6;
    int lr = lane & 15, lg = lane >> 4;
    int proj = blockIdx.x >> 3;
    int nb = (blockIdx.x & 7) * 128;
    int mb = blockIdx.y * 128;
    int wm = (w >> 1) * 64, wn = (w & 1) * 64;

    const unsigned short* Ap = A + (size_t)proj * (4096 * 1024);
    const unsigned short* Bp = B + (size_t)proj * (1024 * 1024);
    const float* bias = (proj == 0) ? bias0 : (proj == 1) ? bias1 : bias2;
    float scale = (proj < 2) ? scale01 : scale2;

    int c0 = w * 64 + lane;
    int r0 = c0 >> 2, e0 = (c0 & 3) * 8;
    int r1 = r0 + 64;
    const unsigned short* gA0 = Ap + (size_t)(mb + r0) * HSZ + e0;
    const unsigned short* gA1 = Ap + (size_t)(mb + r1) * HSZ + e0;
    const unsigned short* gB0 = Bp + (size_t)(nb + r0) * HSZ + e0;
    const unsigned short* gB1 = Bp + (size_t)(nb + r1) * HSZ + e0;
    unsigned short* lA0 = As + w * 512;
    unsigned short* lA1 = As + 2048 + w * 512;
    unsigned short* lB0 = Bs + w * 512;
    unsigned short* lB1 = Bs + 2048 + w * 512;

    f32x4 acc[4][4] = {};

    for (int kt = 0; kt < HSZ; kt += 32) {
        gload_lds16(gA0 + kt, lA0);
        gload_lds16(gA1 + kt, lA1);
        gload_lds16(gB0 + kt, lB0);
        gload_lds16(gB1 + kt, lB1);
        __syncthreads();

        short8v af[4], bfv[4];
#pragma unroll
        for (int s = 0; s < 4; s++) {
            af[s]  = *(const short8v*)&As[(wm + s * 16 + lr) * 32 + lg * 8];
            bfv[s] = *(const short8v*)&Bs[(wn + s * 16 + lr) * 32 + lg * 8];
        }
#pragma unroll
        for (int i = 0; i < 4; i++)
#pragma unroll
            for (int j = 0; j < 4; j++)
                acc[i][j] = __builtin_amdgcn_mfma_f32_16x16x32_bf16(af[i], bfv[j], acc[i][j], 0, 0, 0);
        __syncthreads();
    }

#pragma unroll
    for (int j = 0; j < 4; j++) {
        int col = nb + wn + j * 16 + lr;
        float bv = bias[col];
#pragma unroll
        for (int i = 0; i < 4; i++) {
            int row0 = mb + wm + i * 16 + lg * 4;
#pragma unroll
            for (int rg = 0; rg < 4; rg++) {
                float v = (acc[i][j][rg] + bv) * scale;
                if (OUTF32)
                    ((float*)outbase)[(size_t)(row0 + rg) * HSZ + col] = v;
                else
                    ((unsigned short*)outbase)[(size_t)proj * (4096 * 1024) +
                                               (size_t)(row0 + rg) * HSZ + col] = f2bf(v);
            }
        }
    }
}

// ---------------------------------------------------------------------------
// Legacy fp32-A GEMM (fallback path if ws is small).
// ---------------------------------------------------------------------------
template<bool ABF16, bool OUTBF16>
__global__ __launch_bounds__(256) void gemm_bt_kernel(
    const void* __restrict__ Aptr, const unsigned short* __restrict__ Bt,
    const float* __restrict__ bias, float scale, void* __restrict__ outp)
{
    __shared__ __align__(16) unsigned short As[128][40];
    __shared__ __align__(16) unsigned short Bs[128][40];

    int t = threadIdx.x;
    int lane = t & 63, w = t >> 6;
    int lr = lane & 15, lg = lane >> 4;
    int mb = blockIdx.y * 128, nb = blockIdx.x * 128;
    int wm = (w >> 1) * 64, wn = (w & 1) * 64;
    int r = t >> 1, cc = (t & 1) * 16;

    f32x4 acc[4][4] = {};

    for (int kt = 0; kt < HSZ; kt += 32) {
        if (ABF16) {
            const unsigned short* A = (const unsigned short*)Aptr + (size_t)(mb + r) * HSZ + kt + cc;
            *(uint4*)&As[r][cc]     = ((const uint4*)A)[0];
            *(uint4*)&As[r][cc + 8] = ((const uint4*)A)[1];
        } else {
            const float* A = (const float*)Aptr + (size_t)(mb + r) * HSZ + kt + cc;
            unsigned short tmp[16];
#pragma unroll
            for (int q = 0; q < 4; q++) {
                float4 v = ((const float4*)A)[q];
                tmp[q * 4 + 0] = f2bf(v.x); tmp[q * 4 + 1] = f2bf(v.y);
                tmp[q * 4 + 2] = f2bf(v.z); tmp[q * 4 + 3] = f2bf(v.w);
            }
            *(uint4*)&As[r][cc]     = *(uint4*)&tmp[0];
            *(uint4*)&As[r][cc + 8] = *(uint4*)&tmp[8];
        }
        {
            const unsigned short* B = Bt + (size_t)(nb + r) * HSZ + kt + cc;
            *(uint4*)&Bs[r][cc]     = ((const uint4*)B)[0];
            *(uint4*)&Bs[r][cc + 8] = ((const uint4*)B)[1];
        }
        __syncthreads();

        short8v af[4], bf[4];
#pragma unroll
        for (int s = 0; s < 4; s++) af[s] = *(const short8v*)&As[wm + s * 16 + lr][8 * lg];
#pragma unroll
        for (int s = 0; s < 4; s++) bf[s] = *(const short8v*)&Bs[wn + s * 16 + lr][8 * lg];
#pragma unroll
        for (int i = 0; i < 4; i++)
#pragma unroll
            for (int j = 0; j < 4; j++)
                acc[i][j] = __builtin_amdgcn_mfma_f32_16x16x32_bf16(af[i], bf[j], acc[i][j], 0, 0, 0);
        __syncthreads();
    }

#pragma unroll
    for (int j = 0; j < 4; j++) {
        int col = nb + wn + j * 16 + lr;
        float bv = bias[col];
#pragma unroll
        for (int i = 0; i < 4; i++) {
            int row0 = mb + wm + i * 16 + lg * 4;
#pragma unroll
            for (int rg = 0; rg < 4; rg++) {
                float v = (acc[i][j][rg] + bv) * scale;
                if (OUTBF16)
                    ((unsigned short*)outp)[(size_t)(row0 + rg) * HSZ + col] = f2bf(v);
                else
                    ((float*)outp)[(size_t)(row0 + rg) * HSZ + col] = v;
            }
        }
    }
}

// ---------------------------------------------------------------------------
// Phase 1: rcpC[head][j] = 1 / sum_{i>=j} exp(S_ij). S^T = mfma(K,Q).
// 1D grid with XCD remap: 4 heads per XCD (K/Q panels L2-resident).
// ---------------------------------------------------------------------------
__global__ __launch_bounds__(256) void colsum_kernel(
    const unsigned short* __restrict__ Qb, const unsigned short* __restrict__ Kb,
    float* __restrict__ rcpC)
{
    int raw = blockIdx.x;
    int xcd = raw & 7, idx = raw >> 3;        // idx in [0,128)
    int head = xcd * 4 + (idx >> 5);          // 4 heads per XCD
    int jb = (idx & 31) * 64;
    const unsigned short* Qh = Qb + (size_t)head * L * HDIM;
    const unsigned short* Kh = Kb + (size_t)head * L * HDIM;
    int t = threadIdx.x, lane = t & 63, w = t >> 6;
    int lr = lane & 15, lg = lane >> 4;

    short8v af[4][2];
#pragma unroll
    for (int sj = 0; sj < 4; sj++)
#pragma unroll
        for (int kk = 0; kk < 2; kk++)
            af[sj][kk] = *(const short8v*)&Kh[(size_t)(jb + sj * 16 + lr) * HDIM + kk * 32 + 8 * lg];

    float accs[4][4] = {};

    int it0 = jb + w * 16;
    short8v bc0 = *(const short8v*)&Qh[(size_t)(it0 + lr) * HDIM + 8 * lg];
    short8v bc1 = *(const short8v*)&Qh[(size_t)(it0 + lr) * HDIM + 32 + 8 * lg];

    for (int it = it0; it < L; it += 64) {
        int itn = (it + 64 < L) ? it + 64 : it;
        short8v bn0 = *(const short8v*)&Qh[(size_t)(itn + lr) * HDIM + 8 * lg];
        short8v bn1 = *(const short8v*)&Qh[(size_t)(itn + lr) * HDIM + 32 + 8 * lg];
        int i = it + lr;
#pragma unroll
        for (int sj = 0; sj < 4; sj++) {
            f32x4 d = {0.0f, 0.0f, 0.0f, 0.0f};
            d = __builtin_amdgcn_mfma_f32_16x16x32_bf16(af[sj][0], bc0, d, 0, 0, 0);
            d = __builtin_amdgcn_mfma_f32_16x16x32_bf16(af[sj][1], bc1, d, 0, 0, 0);
#pragma unroll
            for (int rg = 0; rg < 4; rg++) {
                int j = jb + sj * 16 + lg * 4 + rg;
                if (i >= j) accs[sj][rg] += __expf(d[rg]);
            }
        }
        bc0 = bn0; bc1 = bn1;
    }

    __shared__ float part[4][64];
#pragma unroll
    for (int sj = 0; sj < 4; sj++)
#pragma unroll
        for (int rg = 0; rg < 4; rg++) {
            float v = accs[sj][rg];
            v += __shfl_xor(v, 1); v += __shfl_xor(v, 2);
            v += __shfl_xor(v, 4); v += __shfl_xor(v, 8);
            if (lr == 0) part[w][sj * 16 + lg * 4 + rg] = v;
        }
    __syncthreads();
    if (t < 64) {
        float s = part[0][t] + part[1][t] + part[2][t] + part[3][t];
        rcpC[(size_t)head * L + jb + t] = 1.0f / s;
    }
}

// ---------------------------------------------------------------------------
// V transpose with rcpC folded: Vt[p][c][j] = bf16(V[p][j][c] * rcpC[p][j]).
// ---------------------------------------------------------------------------
__global__ __launch_bounds__(256) void vtrans_kernel(
    const unsigned short* __restrict__ Vb, const float* __restrict__ rcpC,
    unsigned short* __restrict__ Vt)
{
    int p = blockIdx.y;
    int j0 = blockIdx.x * 64;
    const unsigned short* Vp = Vb + (size_t)p * L * HDIM;
    unsigned short* Tp = Vt + (size_t)p * HDIM * L;
    __shared__ __align__(16) unsigned short tl[64][72];
    int t = threadIdx.x;
    int jl = t >> 2, c0 = (t & 3) * 16;
    float rcv = rcpC[(size_t)p * L + j0 + jl];
    const unsigned short* src = Vp + (size_t)(j0 + jl) * HDIM + c0;
    unsigned short raw[16];
    *(uint4*)&raw[0] = ((const uint4*)src)[0];
    *(uint4*)&raw[8] = ((const uint4*)src)[1];
#pragma unroll
    for (int e = 0; e < 16; e++) tl[jl][c0 + e] = f2bf(bf2f(raw[e]) * rcv);
    __syncthreads();
    int cl = t >> 2, jc = (t & 3) * 16;
    unsigned short tmp[16];
#pragma unroll
    for (int e = 0; e < 16; e++) tmp[e] = tl[jc + e][cl];
    unsigned short* dst = Tp + (size_t)cl * L + j0 + jc;
    ((uint4*)dst)[0] = *(uint4*)&tmp[0];
    ((uint4*)dst)[1] = *(uint4*)&tmp[8];
}

// ---------------------------------------------------------------------------
// Phase 2 (LDS-staged flash loop): block = 4 waves x 32 q-rows = 128 rows.
// Per KV-tile (64 j): K-tile [64][64] and V^T-tile [64][64] staged once into
// XOR-swizzled LDS (inverse-swizzled global source, linear gload_lds dest;
// swizzle = byte ^ (row&7)<<4), double-buffered, one barrier per tile.
// Waves read fragments via swizzled ds_read_b128 (bank-balanced), compute
// QK^T -> exp -> cvt_pk/shfl -> PV exactly as the verified R3 machinery.
// XCD remap: 4 heads/XCD; snake pairing of q-tiles balances per-CU work.
// ---------------------------------------------------------------------------
__global__ __launch_bounds__(256) void attn_kernel(
    const unsigned short* __restrict__ Qb, const unsigned short* __restrict__ Kb,
    const unsigned short* __restrict__ Vtg, unsigned short* __restrict__ Ctx)
{
    int raw = blockIdx.x;
    int xcd = raw & 7, idx = raw >> 3;            // idx in [0,64)
    int head = xcd * 4 + (idx >> 4);              // 4 heads per XCD
    int jpos = idx & 15;
    int qtile = (jpos & 1) ? (jpos >> 1) : (15 - (jpos >> 1));   // snake
    int qb = qtile * 128;
    int nt = qb / 64 + 2;                          // KV tiles this block touches

    const unsigned short* Qh = Qb + (size_t)head * L * HDIM;
    const unsigned short* Kh = Kb + (size_t)head * L * HDIM;
    const unsigned short* Vh = Vtg + (size_t)head * HDIM * L;   // [64][2048]
    unsigned short* Ch = Ctx + (size_t)head * L * HDIM;

    int t = threadIdx.x;
    int lane = t & 63, w = t >> 6;
    int lr = lane & 15, lg = lane >> 4;
    int iw = qb + w * 32;
    int src0 = ((lane & 16) << 1) + lr;
    int src1 = src0 + 16;
    bool jlow = (lg < 2);
    int lastT = nt - 2 + (w >> 1);                 // last tile this wave computes

    __shared__ __align__(16) unsigned short Kt[2][4096];
    __shared__ __align__(16) unsigned short Vl[2][4096];

    // staging geometry: lane writes 16B at linear LDS (row = w*8+lane/8 [+32],
    // byte x = (lane&7)*16); source pre-XORed so LDS[row][x] = G[row][x^swz(row)]
    int srow = w * 8 + (lane >> 3);
    int soff = ((lane & 7) ^ (lane >> 3)) * 8;     // ushort offset in row

    // Q as B-fragment (registers, hoisted)
    short8v bq[2][2];
#pragma unroll
    for (int isub = 0; isub < 2; isub++)
#pragma unroll
        for (int kd = 0; kd < 2; kd++)
            bq[isub][kd] = *(const short8v*)&Qh[(size_t)(iw + isub * 16 + lr) * HDIM + kd * 32 + 8 * lg];

    f32x4 acc[4][2] = {};   // ctx^T [csub][isub]: D(c=lg*4+rg, i=lr)

    // prologue: stage tile 0 into buf 0
    {
        gload_lds16(Kh + (size_t)srow * HDIM + soff,        &Kt[0][w * 512]);
        gload_lds16(Kh + (size_t)(srow + 32) * HDIM + soff, &Kt[0][w * 512 + 2048]);
        gload_lds16(Vh + (size_t)srow * L + soff,           &Vl[0][w * 512]);
        gload_lds16(Vh + (size_t)(srow + 32) * L + soff,    &Vl[0][w * 512 + 2048]);
    }
    __syncthreads();   // compiler drains vmcnt before barrier

    for (int tt = 0; tt < nt; ++tt) {
        int buf = tt & 1;
        if (tt + 1 < nt) {   // issue next tile's stage (lands by next barrier)
            int jt = (tt + 1) * 64;
            int nbuf = buf ^ 1;
            gload_lds16(Kh + (size_t)(jt + srow) * HDIM + soff,        &Kt[nbuf][w * 512]);
            gload_lds16(Kh + (size_t)(jt + srow + 32) * HDIM + soff,   &Kt[nbuf][w * 512 + 2048]);
            gload_lds16(Vh + (size_t)srow * L + jt + soff,             &Vl[nbuf][w * 512]);
            gload_lds16(Vh + (size_t)(srow + 32) * L + jt + soff,      &Vl[nbuf][w * 512 + 2048]);
        }
        if (tt <= lastT) {
#pragma unroll
            for (int w2 = 0; w2 < 2; ++w2) {
                int jt32 = tt * 64 + w2 * 32;
                if (jt32 <= iw + 31) {
                    // K fragments from swizzled LDS
                    short8v ak[2][2];
#pragma unroll
                    for (int jsub = 0; jsub < 2; jsub++)
#pragma unroll
                        for (int kd = 0; kd < 2; kd++) {
                            int lrow = w2 * 32 + jsub * 16 + lr;
                            int off = lrow * 64 + ((((kd << 2) | lg) ^ (lr & 7)) << 3);
                            ak[jsub][kd] = *(const short8v*)&Kt[buf][off];
                        }
                    short8v av[4];
#pragma unroll
                    for (int csub = 0; csub < 4; csub++) {
                        int vrow = csub * 16 + lr;
                        int off = vrow * 64 + ((((w2 << 2) | lg) ^ (lr & 7)) << 3);
                        av[csub] = *(const short8v*)&Vl[buf][off];
                    }

                    unsigned int pk[2][2][2];   // [jsub][isub][word]
#pragma unroll
                    for (int jsub = 0; jsub < 2; jsub++)
#pragma unroll
                        for (int isub = 0; isub < 2; isub++) {
                            f32x4 s = {0.0f, 0.0f, 0.0f, 0.0f};
                            s = __builtin_amdgcn_mfma_f32_16x16x32_bf16(ak[jsub][0], bq[isub][0], s, 0, 0, 0);
                            s = __builtin_amdgcn_mfma_f32_16x16x32_bf16(ak[jsub][1], bq[isub][1], s, 0, 0, 0);
                            int i = iw + isub * 16 + lr;
                            int jb0 = jt32 + jsub * 16 + lg * 4;
                            float p[4];
#pragma unroll
                            for (int rg = 0; rg < 4; rg++)
                                p[rg] = (jb0 + rg <= i) ? __expf(s[rg]) : 0.0f;
                            pk[jsub][isub][0] = cvt_pk_bf16(p[0], p[1]);
                            pk[jsub][isub][1] = cvt_pk_bf16(p[2], p[3]);
                        }
                    __builtin_amdgcn_s_setprio(1);
#pragma unroll
                    for (int isub = 0; isub < 2; isub++) {
                        int a0 = __shfl((int)pk[0][isub][0], src0);
                        int a1 = __shfl((int)pk[0][isub][1], src0);
                        int a2 = __shfl((int)pk[0][isub][0], src1);
                        int a3 = __shfl((int)pk[0][isub][1], src1);
                        int b0 = __shfl((int)pk[1][isub][0], src0);
                        int b1 = __shfl((int)pk[1][isub][1], src0);
                        int b2 = __shfl((int)pk[1][isub][0], src1);
                        int b3 = __shfl((int)pk[1][isub][1], src1);
                        int4 wvv;
                        wvv.x = jlow ? a0 : b0;
                        wvv.y = jlow ? a1 : b1;
                        wvv.z = jlow ? a2 : b2;
                        wvv.w = jlow ? a3 : b3;
                        short8v bp = __builtin_bit_cast(short8v, wvv);
#pragma unroll
                        for (int csub = 0; csub < 4; csub++)
                            acc[csub][isub] = __builtin_amdgcn_mfma_f32_16x16x32_bf16(av[csub], bp, acc[csub][isub], 0, 0, 0);
                    }
                    __builtin_amdgcn_s_setprio(0);
                }
            }
        }
        __syncthreads();   // stage(t+1) drained + all reads of buf done
    }

    // epilogue: element (c = csub*16+lg*4+rg, i = iw+isub*16+lr), 8B stores
#pragma unroll
    for (int csub = 0; csub < 4; csub++)
#pragma unroll
        for (int isub = 0; isub < 2; isub++) {
            int i = iw + isub * 16 + lr;
            int c0 = csub * 16 + lg * 4;
            unsigned short t4[4];
#pragma unroll
            for (int rg = 0; rg < 4; rg++) t4[rg] = f2bf(acc[csub][isub][rg]);
            *(uint2*)&Ch[(size_t)i * HDIM + c0] = *(uint2*)t4;
        }
}

// ---------------------------------------------------------------------------
extern "C" void kernel_launch(void* const* d_in, const int* in_sizes, int n_in,
                              void* d_out, int out_size, void* d_ws, size_t ws_size,
                              hipStream_t stream)
{
    const float* H_q = (const float*)d_in[0];
    const float* H_k = (const float*)d_in[1];
    const float* H_v = (const float*)d_in[2];
    const float* W_q = (const float*)d_in[3];
    const float* b_q = (const float*)d_in[4];
    const float* W_k = (const float*)d_in[5];
    const float* b_k = (const float*)d_in[6];
    const float* W_v = (const float*)d_in[7];
    const float* b_v = (const float*)d_in[8];
    const float* W_o = (const float*)d_in[9];
    const float* b_o = (const float*)d_in[10];

    char* ws = (char*)d_ws;
    const size_t MB = (size_t)1 << 20;
    const float scale = 0.03125f;  // 1/sqrt(1024)

    if (ws_size >= 60 * MB) {
        unsigned short* Hbf = (unsigned short*)(ws);
        unsigned short* Vt  = (unsigned short*)(ws);
        unsigned short* Ctx = (unsigned short*)(ws + 8 * MB);
        unsigned short* Wt4 = (unsigned short*)(ws + 24 * MB);
        unsigned short* Qb  = (unsigned short*)(ws + 32 * MB);
        unsigned short* Kb  = (unsigned short*)(ws + 40 * MB);
        unsigned short* Vb  = (unsigned short*)(ws + 48 * MB);
        float* rcpC = (float*)(ws + 56 * MB);

        wtrans_kernel<<<dim3(16, 16, 4), 256, 0, stream>>>(W_q, W_k, W_v, W_o, Wt4);
        hconv_kernel<<<dim3(2048, 3), 256, 0, stream>>>(H_q, H_k, H_v, Hbf);
        gemm_glds_kernel<false><<<dim3(24, 32), 256, 0, stream>>>(
            Hbf, Wt4, b_q, b_k, b_v, scale, 1.0f, Qb);
        colsum_kernel<<<1024, 256, 0, stream>>>(Qb, Kb, rcpC);
        vtrans_kernel<<<dim3(32, 32), 256, 0, stream>>>(Vb, rcpC, Vt);
        attn_kernel<<<512, 256, 0, stream>>>(Qb, Kb, Vt, Ctx);
        gemm_glds_kernel<true><<<dim3(8, 32), 256, 0, stream>>>(
            Ctx, Wt4 + (size_t)3 * 1024 * 1024, b_o, b_o, b_o, 1.0f, 1.0f, d_out);
    } else {
        unsigned short* Qb  = (unsigned short*)(ws + 0 * MB);
        unsigned short* Kb  = (unsigned short*)(ws + 8 * MB);
        unsigned short* Vt  = (unsigned short*)(ws + 16 * MB);
        unsigned short* Vb  = (unsigned short*)(ws + 24 * MB);
        unsigned short* Ctx = (unsigned short*)(ws + 24 * MB);
        unsigned short* Wt4 = (unsigned short*)(ws + 32 * MB);
        float* rcpC = (float*)(ws + 40 * MB);

        wtrans_kernel<<<dim3(16, 16, 4), 256, 0, stream>>>(W_q, W_k, W_v, W_o, Wt4);
        gemm_bt_kernel<false, true><<<dim3(8, 32), 256, 0, stream>>>(H_q, Wt4, b_q, scale, Qb);
        gemm_bt_kernel<false, true><<<dim3(8, 32), 256, 0, stream>>>(H_k, Wt4 + (size_t)1024 * 1024, b_k, scale, Kb);
        gemm_bt_kernel<false, true><<<dim3(8, 32), 256, 0, stream>>>(H_v, Wt4 + (size_t)2 * 1024 * 1024, b_v, 1.0f, Vb);
        colsum_kernel<<<1024, 256, 0, stream>>>(Qb, Kb, rcpC);
        vtrans_kernel<<<dim3(32, 32), 256, 0, stream>>>(Vb, rcpC, Vt);
        attn_kernel<<<512, 256, 0, stream>>>(Qb, Kb, Vt, Ctx);
        gemm_bt_kernel<true, false><<<dim3(8, 32), 256, 0, stream>>>(Ctx, Wt4 + (size_t)3 * 1024 * 1024, b_o, 1.0f, d_out);
    }
}

// Round 7
// 172.321 us; speedup vs baseline: 1.8822x; 1.0905x over previous
//
#include <hip/hip_runtime.h>

#define L 2048
#define HSZ 1024
#define HDIM 64
// 32 head-panels total (N=2 batches x 16 heads), each a contiguous [2048][64]

typedef float f32x4 __attribute__((ext_vector_type(4)));
typedef short short8v __attribute__((ext_vector_type(8)));

static __device__ __forceinline__ unsigned short f2bf(float f) {
    unsigned int u = __builtin_bit_cast(unsigned int, f);
    u += 0x7FFFu + ((u >> 16) & 1u);   // RNE
    return (unsigned short)(u >> 16);
}
static __device__ __forceinline__ float bf2f(unsigned short u) {
    return __builtin_bit_cast(float, (unsigned int)u << 16);
}
static __device__ __forceinline__ unsigned int cvt_pk_bf16(float lo, float hi) {
    unsigned int r;
    asm("v_cvt_pk_bf16_f32 %0, %1, %2" : "=v"(r) : "v"(lo), "v"(hi));
    return r;
}
static __device__ __forceinline__ void gload_lds16(const void* g, void* l) {
    __builtin_amdgcn_global_load_lds(
        (const __attribute__((address_space(1))) unsigned int*)g,
        (__attribute__((address_space(3))) unsigned int*)l, 16, 0, 0);
}

// ---------------------------------------------------------------------------
// Weights: Wt4[z][n][k] = bf16(W_z[k][n]) for z in {q,k,v,o}.
// ---------------------------------------------------------------------------
__global__ __launch_bounds__(256) void wtrans_kernel(
    const float* __restrict__ W0, const float* __restrict__ W1,
    const float* __restrict__ W2, const float* __restrict__ W3,
    unsigned short* __restrict__ Wt4)
{
    const float* W;
    int z = blockIdx.z;
    if (z == 0) W = W0; else if (z == 1) W = W1; else if (z == 2) W = W2; else W = W3;
    unsigned short* T = Wt4 + (size_t)z * HSZ * HSZ;

    __shared__ __align__(16) unsigned short tl[64][72];
    int t = threadIdx.x;
    int k0 = blockIdx.y * 64, n0 = blockIdx.x * 64;

    int kl = t >> 2, nc = (t & 3) * 16;
    const float* src = W + (size_t)(k0 + kl) * HSZ + n0 + nc;
#pragma unroll
    for (int q = 0; q < 4; q++) {
        float4 v = ((const float4*)src)[q];
        tl[kl][nc + q * 4 + 0] = f2bf(v.x);
        tl[kl][nc + q * 4 + 1] = f2bf(v.y);
        tl[kl][nc + q * 4 + 2] = f2bf(v.z);
        tl[kl][nc + q * 4 + 3] = f2bf(v.w);
    }
    __syncthreads();
    int nl = t >> 2, kc = (t & 3) * 16;
    unsigned short tmp[16];
#pragma unroll
    for (int e = 0; e < 16; e++) tmp[e] = tl[kc + e][nl];
    unsigned short* dst = T + (size_t)(n0 + nl) * HSZ + k0 + kc;
    ((uint4*)dst)[0] = *(uint4*)&tmp[0];
    ((uint4*)dst)[1] = *(uint4*)&tmp[8];
}

// ---------------------------------------------------------------------------
// Convert H_q/H_k/H_v fp32 -> bf16 into contiguous Hbf[3][4096][1024].
// ---------------------------------------------------------------------------
__global__ __launch_bounds__(256) void hconv_kernel(
    const float* __restrict__ H0, const float* __restrict__ H1,
    const float* __restrict__ H2, unsigned short* __restrict__ Hbf)
{
    int z = blockIdx.y;
    const float* S = (z == 0) ? H0 : (z == 1) ? H1 : H2;
    size_t base = ((size_t)blockIdx.x * 256 + threadIdx.x) * 8;
    unsigned short* D = Hbf + (size_t)z * (4096 * 1024) + base;
    float4 a = *(const float4*)(S + base);
    float4 b = *(const float4*)(S + base + 4);
    unsigned short o[8] = {f2bf(a.x), f2bf(a.y), f2bf(a.z), f2bf(a.w),
                           f2bf(b.x), f2bf(b.y), f2bf(b.z), f2bf(b.w)};
    *(uint4*)D = *(const uint4*)o;
}

// ---------------------------------------------------------------------------
// m97-style GEMM, T3-minimum single-barrier dbuf pipeline:
// stage(t+1) issued BEFORE compute(t); one __syncthreads per K-step (its
// vmcnt drain completes the prefetch). Ping-pong 2x(8KB A + 8KB B) LDS.
// ---------------------------------------------------------------------------
template<bool OUTF32>
__global__ __launch_bounds__(256) void gemm_glds_kernel(
    const unsigned short* __restrict__ A, const unsigned short* __restrict__ B,
    const float* __restrict__ bias0, const float* __restrict__ bias1,
    const float* __restrict__ bias2, float scale01, float scale2,
    void* __restrict__ outbase)
{
    __shared__ __align__(16) unsigned short As[2][4096];
    __shared__ __align__(16) unsigned short Bs[2][4096];

    int t = threadIdx.x;
    int lane = t & 63, w = t >> 6;
    int lr = lane & 15, lg = lane >> 4;
    int proj = blockIdx.x >> 3;
    int nb = (blockIdx.x & 7) * 128;
    int mb = blockIdx.y * 128;
    int wm = (w >> 1) * 64, wn = (w & 1) * 64;

    const unsigned short* Ap = A + (size_t)proj * (4096 * 1024);
    const unsigned short* Bp = B + (size_t)proj * (1024 * 1024);
    const float* bias = (proj == 0) ? bias0 : (proj == 1) ? bias1 : bias2;
    float scale = (proj < 2) ? scale01 : scale2;

    int c0 = w * 64 + lane;
    int r0 = c0 >> 2, e0 = (c0 & 3) * 8;
    int r1 = r0 + 64;
    const unsigned short* gA0 = Ap + (size_t)(mb + r0) * HSZ + e0;
    const unsigned short* gA1 = Ap + (size_t)(mb + r1) * HSZ + e0;
    const unsigned short* gB0 = Bp + (size_t)(nb + r0) * HSZ + e0;
    const unsigned short* gB1 = Bp + (size_t)(nb + r1) * HSZ + e0;

    f32x4 acc[4][4] = {};

    auto stage = [&](int buf, int kt) {
        gload_lds16(gA0 + kt, &As[buf][w * 512]);
        gload_lds16(gA1 + kt, &As[buf][2048 + w * 512]);
        gload_lds16(gB0 + kt, &Bs[buf][w * 512]);
        gload_lds16(gB1 + kt, &Bs[buf][2048 + w * 512]);
    };

    stage(0, 0);
    __syncthreads();

    int buf = 0;
    for (int kt = 0; kt < HSZ; kt += 32) {
        if (kt + 32 < HSZ) stage(buf ^ 1, kt + 32);

        short8v af[4], bfv[4];
#pragma unroll
        for (int s = 0; s < 4; s++) {
            af[s]  = *(const short8v*)&As[buf][(wm + s * 16 + lr) * 32 + lg * 8];
            bfv[s] = *(const short8v*)&Bs[buf][(wn + s * 16 + lr) * 32 + lg * 8];
        }
#pragma unroll
        for (int i = 0; i < 4; i++)
#pragma unroll
            for (int j = 0; j < 4; j++)
                acc[i][j] = __builtin_amdgcn_mfma_f32_16x16x32_bf16(af[i], bfv[j], acc[i][j], 0, 0, 0);
        __syncthreads();   // drains stage vmcnt + all reads of buf
        buf ^= 1;
    }

#pragma unroll
    for (int j = 0; j < 4; j++) {
        int col = nb + wn + j * 16 + lr;
        float bv = bias[col];
#pragma unroll
        for (int i = 0; i < 4; i++) {
            int row0 = mb + wm + i * 16 + lg * 4;
#pragma unroll
            for (int rg = 0; rg < 4; rg++) {
                float v = (acc[i][j][rg] + bv) * scale;
                if (OUTF32)
                    ((float*)outbase)[(size_t)(row0 + rg) * HSZ + col] = v;
                else
                    ((unsigned short*)outbase)[(size_t)proj * (4096 * 1024) +
                                               (size_t)(row0 + rg) * HSZ + col] = f2bf(v);
            }
        }
    }
}

// ---------------------------------------------------------------------------
// Legacy fp32-A GEMM (fallback path if ws is small).
// ---------------------------------------------------------------------------
template<bool ABF16, bool OUTBF16>
__global__ __launch_bounds__(256) void gemm_bt_kernel(
    const void* __restrict__ Aptr, const unsigned short* __restrict__ Bt,
    const float* __restrict__ bias, float scale, void* __restrict__ outp)
{
    __shared__ __align__(16) unsigned short As[128][40];
    __shared__ __align__(16) unsigned short Bs[128][40];

    int t = threadIdx.x;
    int lane = t & 63, w = t >> 6;
    int lr = lane & 15, lg = lane >> 4;
    int mb = blockIdx.y * 128, nb = blockIdx.x * 128;
    int wm = (w >> 1) * 64, wn = (w & 1) * 64;
    int r = t >> 1, cc = (t & 1) * 16;

    f32x4 acc[4][4] = {};

    for (int kt = 0; kt < HSZ; kt += 32) {
        if (ABF16) {
            const unsigned short* A = (const unsigned short*)Aptr + (size_t)(mb + r) * HSZ + kt + cc;
            *(uint4*)&As[r][cc]     = ((const uint4*)A)[0];
            *(uint4*)&As[r][cc + 8] = ((const uint4*)A)[1];
        } else {
            const float* A = (const float*)Aptr + (size_t)(mb + r) * HSZ + kt + cc;
            unsigned short tmp[16];
#pragma unroll
            for (int q = 0; q < 4; q++) {
                float4 v = ((const float4*)A)[q];
                tmp[q * 4 + 0] = f2bf(v.x); tmp[q * 4 + 1] = f2bf(v.y);
                tmp[q * 4 + 2] = f2bf(v.z); tmp[q * 4 + 3] = f2bf(v.w);
            }
            *(uint4*)&As[r][cc]     = *(uint4*)&tmp[0];
            *(uint4*)&As[r][cc + 8] = *(uint4*)&tmp[8];
        }
        {
            const unsigned short* B = Bt + (size_t)(nb + r) * HSZ + kt + cc;
            *(uint4*)&Bs[r][cc]     = ((const uint4*)B)[0];
            *(uint4*)&Bs[r][cc + 8] = ((const uint4*)B)[1];
        }
        __syncthreads();

        short8v af[4], bf[4];
#pragma unroll
        for (int s = 0; s < 4; s++) af[s] = *(const short8v*)&As[wm + s * 16 + lr][8 * lg];
#pragma unroll
        for (int s = 0; s < 4; s++) bf[s] = *(const short8v*)&Bs[wn + s * 16 + lr][8 * lg];
#pragma unroll
        for (int i = 0; i < 4; i++)
#pragma unroll
            for (int j = 0; j < 4; j++)
                acc[i][j] = __builtin_amdgcn_mfma_f32_16x16x32_bf16(af[i], bf[j], acc[i][j], 0, 0, 0);
        __syncthreads();
    }

#pragma unroll
    for (int j = 0; j < 4; j++) {
        int col = nb + wn + j * 16 + lr;
        float bv = bias[col];
#pragma unroll
        for (int i = 0; i < 4; i++) {
            int row0 = mb + wm + i * 16 + lg * 4;
#pragma unroll
            for (int rg = 0; rg < 4; rg++) {
                float v = (acc[i][j][rg] + bv) * scale;
                if (OUTBF16)
                    ((unsigned short*)outp)[(size_t)(row0 + rg) * HSZ + col] = f2bf(v);
                else
                    ((float*)outp)[(size_t)(row0 + rg) * HSZ + col] = v;
            }
        }
    }
}

// ---------------------------------------------------------------------------
// Phase 1: rcpC[head][j] = 1 / sum_{i>=j} exp(S_ij). S^T = mfma(K,Q).
// ---------------------------------------------------------------------------
__global__ __launch_bounds__(256) void colsum_kernel(
    const unsigned short* __restrict__ Qb, const unsigned short* __restrict__ Kb,
    float* __restrict__ rcpC)
{
    int raw = blockIdx.x;
    int xcd = raw & 7, idx = raw >> 3;        // idx in [0,128)
    int head = xcd * 4 + (idx >> 5);          // 4 heads per XCD
    int jb = (idx & 31) * 64;
    const unsigned short* Qh = Qb + (size_t)head * L * HDIM;
    const unsigned short* Kh = Kb + (size_t)head * L * HDIM;
    int t = threadIdx.x, lane = t & 63, w = t >> 6;
    int lr = lane & 15, lg = lane >> 4;

    short8v af[4][2];
#pragma unroll
    for (int sj = 0; sj < 4; sj++)
#pragma unroll
        for (int kk = 0; kk < 2; kk++)
            af[sj][kk] = *(const short8v*)&Kh[(size_t)(jb + sj * 16 + lr) * HDIM + kk * 32 + 8 * lg];

    float accs[4][4] = {};

    int it0 = jb + w * 16;
    short8v bc0 = *(const short8v*)&Qh[(size_t)(it0 + lr) * HDIM + 8 * lg];
    short8v bc1 = *(const short8v*)&Qh[(size_t)(it0 + lr) * HDIM + 32 + 8 * lg];

    for (int it = it0; it < L; it += 64) {
        int itn = (it + 64 < L) ? it + 64 : it;
        short8v bn0 = *(const short8v*)&Qh[(size_t)(itn + lr) * HDIM + 8 * lg];
        short8v bn1 = *(const short8v*)&Qh[(size_t)(itn + lr) * HDIM + 32 + 8 * lg];
        int i = it + lr;
#pragma unroll
        for (int sj = 0; sj < 4; sj++) {
            f32x4 d = {0.0f, 0.0f, 0.0f, 0.0f};
            d = __builtin_amdgcn_mfma_f32_16x16x32_bf16(af[sj][0], bc0, d, 0, 0, 0);
            d = __builtin_amdgcn_mfma_f32_16x16x32_bf16(af[sj][1], bc1, d, 0, 0, 0);
#pragma unroll
            for (int rg = 0; rg < 4; rg++) {
                int j = jb + sj * 16 + lg * 4 + rg;
                if (i >= j) accs[sj][rg] += __expf(d[rg]);
            }
        }
        bc0 = bn0; bc1 = bn1;
    }

    __shared__ float part[4][64];
#pragma unroll
    for (int sj = 0; sj < 4; sj++)
#pragma unroll
        for (int rg = 0; rg < 4; rg++) {
            float v = accs[sj][rg];
            v += __shfl_xor(v, 1); v += __shfl_xor(v, 2);
            v += __shfl_xor(v, 4); v += __shfl_xor(v, 8);
            if (lr == 0) part[w][sj * 16 + lg * 4 + rg] = v;
        }
    __syncthreads();
    if (t < 64) {
        float s = part[0][t] + part[1][t] + part[2][t] + part[3][t];
        rcpC[(size_t)head * L + jb + t] = 1.0f / s;
    }
}

// ---------------------------------------------------------------------------
// V transpose with rcpC folded: Vt[p][c][j] = bf16(V[p][j][c] * rcpC[p][j]).
// ---------------------------------------------------------------------------
__global__ __launch_bounds__(256) void vtrans_kernel(
    const unsigned short* __restrict__ Vb, const float* __restrict__ rcpC,
    unsigned short* __restrict__ Vt)
{
    int p = blockIdx.y;
    int j0 = blockIdx.x * 64;
    const unsigned short* Vp = Vb + (size_t)p * L * HDIM;
    unsigned short* Tp = Vt + (size_t)p * HDIM * L;
    __shared__ __align__(16) unsigned short tl[64][72];
    int t = threadIdx.x;
    int jl = t >> 2, c0 = (t & 3) * 16;
    float rcv = rcpC[(size_t)p * L + j0 + jl];
    const unsigned short* src = Vp + (size_t)(j0 + jl) * HDIM + c0;
    unsigned short raw[16];
    *(uint4*)&raw[0] = ((const uint4*)src)[0];
    *(uint4*)&raw[8] = ((const uint4*)src)[1];
#pragma unroll
    for (int e = 0; e < 16; e++) tl[jl][c0 + e] = f2bf(bf2f(raw[e]) * rcv);
    __syncthreads();
    int cl = t >> 2, jc = (t & 3) * 16;
    unsigned short tmp[16];
#pragma unroll
    for (int e = 0; e < 16; e++) tmp[e] = tl[jc + e][cl];
    unsigned short* dst = Tp + (size_t)cl * L + j0 + jc;
    ((uint4*)dst)[0] = *(uint4*)&tmp[0];
    ((uint4*)dst)[1] = *(uint4*)&tmp[8];
}

// ---------------------------------------------------------------------------
// Phase 2 (LDS-staged flash loop, 8 waves): block covers 128 q-rows.
// Waves w (0-3) and w+4 split the two 32-j windows of strip (w&3) per KV
// tile; partial ctx summed via LDS dump at the end (exact: denom is
// pre-folded into Vt). Waves 0-3 stage K, waves 4-7 stage Vt; XOR-swizzled
// LDS (inverse-swizzled global source), double-buffered, 1 barrier/tile.
// ---------------------------------------------------------------------------
__global__ __launch_bounds__(512) void attn_kernel(
    const unsigned short* __restrict__ Qb, const unsigned short* __restrict__ Kb,
    const unsigned short* __restrict__ Vtg, unsigned short* __restrict__ Ctx)
{
    int raw = blockIdx.x;
    int xcd = raw & 7, idx = raw >> 3;            // idx in [0,64)
    int head = xcd * 4 + (idx >> 4);              // 4 heads per XCD
    int jpos = idx & 15;
    int qtile = (jpos & 1) ? (jpos >> 1) : (15 - (jpos >> 1));   // snake
    int qb = qtile * 128;
    int nt = qb / 64 + 2;                          // KV tiles this block touches

    const unsigned short* Qh = Qb + (size_t)head * L * HDIM;
    const unsigned short* Kh = Kb + (size_t)head * L * HDIM;
    const unsigned short* Vh = Vtg + (size_t)head * HDIM * L;   // [64][2048]
    unsigned short* Ch = Ctx + (size_t)head * L * HDIM;

    int t = threadIdx.x;
    int lane = t & 63, w = t >> 6;
    int ws = w & 3;                                // strip
    int w2 = w >> 2;                               // which 32-j window
    int lr = lane & 15, lg = lane >> 4;
    int iw = qb + ws * 32;
    int src0 = ((lane & 16) << 1) + lr;
    int src1 = src0 + 16;
    bool jlow = (lg < 2);

    // SMEM[0..1] = Kt dbuf, SMEM[2..3] = Vl dbuf; reused as f32x4 dump at end
    __shared__ __align__(16) unsigned short SMEM[4][4096];

    // staging geometry: 8 rows per gload, row = ws*8 + lane/8 (+32),
    // source pre-XORed so LDS[row][x] = G[row][x ^ ((row&7)*16B)]
    int srow = ws * 8 + (lane >> 3);
    int soff = ((lane & 7) ^ (lane >> 3)) * 8;     // ushort offset in row

    auto stageT = [&](int buf, int jt) {
        if (w < 4) {
            gload_lds16(Kh + (size_t)(jt + srow) * HDIM + soff,      &SMEM[buf][ws * 512]);
            gload_lds16(Kh + (size_t)(jt + srow + 32) * HDIM + soff, &SMEM[buf][ws * 512 + 2048]);
        } else {
            gload_lds16(Vh + (size_t)srow * L + jt + soff,           &SMEM[2 + buf][ws * 512]);
            gload_lds16(Vh + (size_t)(srow + 32) * L + jt + soff,    &SMEM[2 + buf][ws * 512 + 2048]);
        }
    };

    // Q as B-fragment (registers, hoisted)
    short8v bq[2][2];
#pragma unroll
    for (int isub = 0; isub < 2; isub++)
#pragma unroll
        for (int kd = 0; kd < 2; kd++)
            bq[isub][kd] = *(const short8v*)&Qh[(size_t)(iw + isub * 16 + lr) * HDIM + kd * 32 + 8 * lg];

    f32x4 acc[4][2] = {};   // ctx^T [csub][isub]: D(c=lg*4+rg, i=lr)

    stageT(0, 0);
    __syncthreads();

    for (int tt = 0; tt < nt; ++tt) {
        int buf = tt & 1;
        if (tt + 1 < nt) stageT(buf ^ 1, (tt + 1) * 64);

        int jt32 = tt * 64 + w2 * 32;
        if (jt32 <= iw + 31) {
            // K fragments from swizzled LDS
            short8v ak[2][2];
#pragma unroll
            for (int jsub = 0; jsub < 2; jsub++)
#pragma unroll
                for (int kd = 0; kd < 2; kd++) {
                    int lrow = w2 * 32 + jsub * 16 + lr;
                    int off = lrow * 64 + ((((kd << 2) | lg) ^ (lr & 7)) << 3);
                    ak[jsub][kd] = *(const short8v*)&SMEM[buf][off];
                }
            short8v av[4];
#pragma unroll
            for (int csub = 0; csub < 4; csub++) {
                int vrow = csub * 16 + lr;
                int off = vrow * 64 + ((((w2 << 2) | lg) ^ (lr & 7)) << 3);
                av[csub] = *(const short8v*)&SMEM[2 + buf][off];
            }

            unsigned int pk[2][2][2];   // [jsub][isub][word]
#pragma unroll
            for (int jsub = 0; jsub < 2; jsub++)
#pragma unroll
                for (int isub = 0; isub < 2; isub++) {
                    f32x4 s = {0.0f, 0.0f, 0.0f, 0.0f};
                    s = __builtin_amdgcn_mfma_f32_16x16x32_bf16(ak[jsub][0], bq[isub][0], s, 0, 0, 0);
                    s = __builtin_amdgcn_mfma_f32_16x16x32_bf16(ak[jsub][1], bq[isub][1], s, 0, 0, 0);
                    int i = iw + isub * 16 + lr;
                    int jb0 = jt32 + jsub * 16 + lg * 4;
                    float p[4];
#pragma unroll
                    for (int rg = 0; rg < 4; rg++)
                        p[rg] = (jb0 + rg <= i) ? __expf(s[rg]) : 0.0f;
                    pk[jsub][isub][0] = cvt_pk_bf16(p[0], p[1]);
                    pk[jsub][isub][1] = cvt_pk_bf16(p[2], p[3]);
                }
            __builtin_amdgcn_s_setprio(1);
#pragma unroll
            for (int isub = 0; isub < 2; isub++) {
                int a0 = __shfl((int)pk[0][isub][0], src0);
                int a1 = __shfl((int)pk[0][isub][1], src0);
                int a2 = __shfl((int)pk[0][isub][0], src1);
                int a3 = __shfl((int)pk[0][isub][1], src1);
                int b0 = __shfl((int)pk[1][isub][0], src0);
                int b1 = __shfl((int)pk[1][isub][1], src0);
                int b2 = __shfl((int)pk[1][isub][0], src1);
                int b3 = __shfl((int)pk[1][isub][1], src1);
                int4 wvv;
                wvv.x = jlow ? a0 : b0;
                wvv.y = jlow ? a1 : b1;
                wvv.z = jlow ? a2 : b2;
                wvv.w = jlow ? a3 : b3;
                short8v bp = __builtin_bit_cast(short8v, wvv);
#pragma unroll
                for (int csub = 0; csub < 4; csub++)
                    acc[csub][isub] = __builtin_amdgcn_mfma_f32_16x16x32_bf16(av[csub], bp, acc[csub][isub], 0, 0, 0);
            }
            __builtin_amdgcn_s_setprio(0);
        }
        __syncthreads();   // stage(t+1) drained + all reads of buf done
    }

    // cross-wave pair reduction: waves 4-7 dump acc to LDS (lane-interleaved,
    // conflict-free), waves 0-3 add + store.
    uint4* red = (uint4*)SMEM;   // 2048 uint4 = 32 KB
    if (w >= 4) {
#pragma unroll
        for (int csub = 0; csub < 4; csub++)
#pragma unroll
            for (int isub = 0; isub < 2; isub++)
                red[((ws * 8) + csub * 2 + isub) * 64 + lane] =
                    __builtin_bit_cast(uint4, acc[csub][isub]);
    }
    __syncthreads();
    if (w < 4) {
#pragma unroll
        for (int csub = 0; csub < 4; csub++)
#pragma unroll
            for (int isub = 0; isub < 2; isub++)
                acc[csub][isub] += __builtin_bit_cast(f32x4,
                    red[((ws * 8) + csub * 2 + isub) * 64 + lane]);

#pragma unroll
        for (int csub = 0; csub < 4; csub++)
#pragma unroll
            for (int isub = 0; isub < 2; isub++) {
                int i = iw + isub * 16 + lr;
                int c0 = csub * 16 + lg * 4;
                unsigned short t4[4];
#pragma unroll
                for (int rg = 0; rg < 4; rg++) t4[rg] = f2bf(acc[csub][isub][rg]);
                *(uint2*)&Ch[(size_t)i * HDIM + c0] = *(uint2*)t4;
            }
    }
}

// ---------------------------------------------------------------------------
extern "C" void kernel_launch(void* const* d_in, const int* in_sizes, int n_in,
                              void* d_out, int out_size, void* d_ws, size_t ws_size,
                              hipStream_t stream)
{
    const float* H_q = (const float*)d_in[0];
    const float* H_k = (const float*)d_in[1];
    const float* H_v = (const float*)d_in[2];
    const float* W_q = (const float*)d_in[3];
    const float* b_q = (const float*)d_in[4];
    const float* W_k = (const float*)d_in[5];
    const float* b_k = (const float*)d_in[6];
    const float* W_v = (const float*)d_in[7];
    const float* b_v = (const float*)d_in[8];
    const float* W_o = (const float*)d_in[9];
    const float* b_o = (const float*)d_in[10];

    char* ws = (char*)d_ws;
    const size_t MB = (size_t)1 << 20;
    const float scale = 0.03125f;  // 1/sqrt(1024)

    if (ws_size >= 60 * MB) {
        unsigned short* Hbf = (unsigned short*)(ws);
        unsigned short* Vt  = (unsigned short*)(ws);
        unsigned short* Ctx = (unsigned short*)(ws + 8 * MB);
        unsigned short* Wt4 = (unsigned short*)(ws + 24 * MB);
        unsigned short* Qb  = (unsigned short*)(ws + 32 * MB);
        unsigned short* Kb  = (unsigned short*)(ws + 40 * MB);
        unsigned short* Vb  = (unsigned short*)(ws + 48 * MB);
        float* rcpC = (float*)(ws + 56 * MB);

        wtrans_kernel<<<dim3(16, 16, 4), 256, 0, stream>>>(W_q, W_k, W_v, W_o, Wt4);
        hconv_kernel<<<dim3(2048, 3), 256, 0, stream>>>(H_q, H_k, H_v, Hbf);
        gemm_glds_kernel<false><<<dim3(24, 32), 256, 0, stream>>>(
            Hbf, Wt4, b_q, b_k, b_v, scale, 1.0f, Qb);
        colsum_kernel<<<1024, 256, 0, stream>>>(Qb, Kb, rcpC);
        vtrans_kernel<<<dim3(32, 32), 256, 0, stream>>>(Vb, rcpC, Vt);
        attn_kernel<<<512, 512, 0, stream>>>(Qb, Kb, Vt, Ctx);
        gemm_glds_kernel<true><<<dim3(8, 32), 256, 0, stream>>>(
            Ctx, Wt4 + (size_t)3 * 1024 * 1024, b_o, b_o, b_o, 1.0f, 1.0f, d_out);
    } else {
        unsigned short* Qb  = (unsigned short*)(ws + 0 * MB);
        unsigned short* Kb  = (unsigned short*)(ws + 8 * MB);
        unsigned short* Vt  = (unsigned short*)(ws + 16 * MB);
        unsigned short* Vb  = (unsigned short*)(ws + 24 * MB);
        unsigned short* Ctx = (unsigned short*)(ws + 24 * MB);
        unsigned short* Wt4 = (unsigned short*)(ws + 32 * MB);
        float* rcpC = (float*)(ws + 40 * MB);

        wtrans_kernel<<<dim3(16, 16, 4), 256, 0, stream>>>(W_q, W_k, W_v, W_o, Wt4);
        gemm_bt_kernel<false, true><<<dim3(8, 32), 256, 0, stream>>>(H_q, Wt4, b_q, scale, Qb);
        gemm_bt_kernel<false, true><<<dim3(8, 32), 256, 0, stream>>>(H_k, Wt4 + (size_t)1024 * 1024, b_k, scale, Kb);
        gemm_bt_kernel<false, true><<<dim3(8, 32), 256, 0, stream>>>(H_v, Wt4 + (size_t)2 * 1024 * 1024, b_v, 1.0f, Vb);
        colsum_kernel<<<1024, 256, 0, stream>>>(Qb, Kb, rcpC);
        vtrans_kernel<<<dim3(32, 32), 256, 0, stream>>>(Vb, rcpC, Vt);
        attn_kernel<<<512, 512, 0, stream>>>(Qb, Kb, Vt, Ctx);
        gemm_bt_kernel<true, false><<<dim3(8, 32), 256, 0, stream>>>(Ctx, Wt4 + (size_t)3 * 1024 * 1024, b_o, 1.0f, d_out);
    }
}

// Round 8
// 143.978 us; speedup vs baseline: 2.2528x; 1.1969x over previous
//
#include <hip/hip_runtime.h>

#define L 2048
#define HSZ 1024
#define HDIM 64
// 32 head-panels total (N=2 batches x 16 heads), each a contiguous [2048][64]

typedef float f32x4 __attribute__((ext_vector_type(4)));
typedef short short8v __attribute__((ext_vector_type(8)));

static __device__ __forceinline__ unsigned short f2bf(float f) {
    unsigned int u = __builtin_bit_cast(unsigned int, f);
    u += 0x7FFFu + ((u >> 16) & 1u);   // RNE
    return (unsigned short)(u >> 16);
}
static __device__ __forceinline__ float bf2f(unsigned short u) {
    return __builtin_bit_cast(float, (unsigned int)u << 16);
}
static __device__ __forceinline__ unsigned int cvt_pk_bf16(float lo, float hi) {
    unsigned int r;
    asm("v_cvt_pk_bf16_f32 %0, %1, %2" : "=v"(r) : "v"(lo), "v"(hi));
    return r;
}
static __device__ __forceinline__ void gload_lds16(const void* g, void* l) {
    __builtin_amdgcn_global_load_lds(
        (const __attribute__((address_space(1))) unsigned int*)g,
        (__attribute__((address_space(3))) unsigned int*)l, 16, 0, 0);
}

// ---------------------------------------------------------------------------
// Weights: Wt4[z][n][k] = bf16(W_z[k][n]) for z in {q,k,v,o}.
// ---------------------------------------------------------------------------
__global__ __launch_bounds__(256) void wtrans_kernel(
    const float* __restrict__ W0, const float* __restrict__ W1,
    const float* __restrict__ W2, const float* __restrict__ W3,
    unsigned short* __restrict__ Wt4)
{
    const float* W;
    int z = blockIdx.z;
    if (z == 0) W = W0; else if (z == 1) W = W1; else if (z == 2) W = W2; else W = W3;
    unsigned short* T = Wt4 + (size_t)z * HSZ * HSZ;

    __shared__ __align__(16) unsigned short tl[64][72];
    int t = threadIdx.x;
    int k0 = blockIdx.y * 64, n0 = blockIdx.x * 64;

    int kl = t >> 2, nc = (t & 3) * 16;
    const float* src = W + (size_t)(k0 + kl) * HSZ + n0 + nc;
#pragma unroll
    for (int q = 0; q < 4; q++) {
        float4 v = ((const float4*)src)[q];
        tl[kl][nc + q * 4 + 0] = f2bf(v.x);
        tl[kl][nc + q * 4 + 1] = f2bf(v.y);
        tl[kl][nc + q * 4 + 2] = f2bf(v.z);
        tl[kl][nc + q * 4 + 3] = f2bf(v.w);
    }
    __syncthreads();
    int nl = t >> 2, kc = (t & 3) * 16;
    unsigned short tmp[16];
#pragma unroll
    for (int e = 0; e < 16; e++) tmp[e] = tl[kc + e][nl];
    unsigned short* dst = T + (size_t)(n0 + nl) * HSZ + k0 + kc;
    ((uint4*)dst)[0] = *(uint4*)&tmp[0];
    ((uint4*)dst)[1] = *(uint4*)&tmp[8];
}

// ---------------------------------------------------------------------------
// Convert H_q/H_k/H_v fp32 -> bf16 into contiguous Hbf[3][4096][1024].
// ---------------------------------------------------------------------------
__global__ __launch_bounds__(256) void hconv_kernel(
    const float* __restrict__ H0, const float* __restrict__ H1,
    const float* __restrict__ H2, unsigned short* __restrict__ Hbf)
{
    int z = blockIdx.y;
    const float* S = (z == 0) ? H0 : (z == 1) ? H1 : H2;
    size_t base = ((size_t)blockIdx.x * 256 + threadIdx.x) * 8;
    unsigned short* D = Hbf + (size_t)z * (4096 * 1024) + base;
    float4 a = *(const float4*)(S + base);
    float4 b = *(const float4*)(S + base + 4);
    unsigned short o[8] = {f2bf(a.x), f2bf(a.y), f2bf(a.z), f2bf(a.w),
                           f2bf(b.x), f2bf(b.y), f2bf(b.z), f2bf(b.w)};
    *(uint4*)D = *(const uint4*)o;
}

// ---------------------------------------------------------------------------
// m97-style GEMM, single-barrier dbuf pipeline (stage(t+1) before compute(t)).
// ---------------------------------------------------------------------------
template<bool OUTF32>
__global__ __launch_bounds__(256) void gemm_glds_kernel(
    const unsigned short* __restrict__ A, const unsigned short* __restrict__ B,
    const float* __restrict__ bias0, const float* __restrict__ bias1,
    const float* __restrict__ bias2, float scale01, float scale2,
    void* __restrict__ outbase)
{
    __shared__ __align__(16) unsigned short As[2][4096];
    __shared__ __align__(16) unsigned short Bs[2][4096];

    int t = threadIdx.x;
    int lane = t & 63, w = t >> 6;
    int lr = lane & 15, lg = lane >> 4;
    int proj = blockIdx.x >> 3;
    int nb = (blockIdx.x & 7) * 128;
    int mb = blockIdx.y * 128;
    int wm = (w >> 1) * 64, wn = (w & 1) * 64;

    const unsigned short* Ap = A + (size_t)proj * (4096 * 1024);
    const unsigned short* Bp = B + (size_t)proj * (1024 * 1024);
    const float* bias = (proj == 0) ? bias0 : (proj == 1) ? bias1 : bias2;
    float scale = (proj < 2) ? scale01 : scale2;

    int c0 = w * 64 + lane;
    int r0 = c0 >> 2, e0 = (c0 & 3) * 8;
    int r1 = r0 + 64;
    const unsigned short* gA0 = Ap + (size_t)(mb + r0) * HSZ + e0;
    const unsigned short* gA1 = Ap + (size_t)(mb + r1) * HSZ + e0;
    const unsigned short* gB0 = Bp + (size_t)(nb + r0) * HSZ + e0;
    const unsigned short* gB1 = Bp + (size_t)(nb + r1) * HSZ + e0;

    f32x4 acc[4][4] = {};

    auto stage = [&](int buf, int kt) {
        gload_lds16(gA0 + kt, &As[buf][w * 512]);
        gload_lds16(gA1 + kt, &As[buf][2048 + w * 512]);
        gload_lds16(gB0 + kt, &Bs[buf][w * 512]);
        gload_lds16(gB1 + kt, &Bs[buf][2048 + w * 512]);
    };

    stage(0, 0);
    __syncthreads();

    int buf = 0;
    for (int kt = 0; kt < HSZ; kt += 32) {
        if (kt + 32 < HSZ) stage(buf ^ 1, kt + 32);

        short8v af[4], bfv[4];
#pragma unroll
        for (int s = 0; s < 4; s++) {
            af[s]  = *(const short8v*)&As[buf][(wm + s * 16 + lr) * 32 + lg * 8];
            bfv[s] = *(const short8v*)&Bs[buf][(wn + s * 16 + lr) * 32 + lg * 8];
        }
#pragma unroll
        for (int i = 0; i < 4; i++)
#pragma unroll
            for (int j = 0; j < 4; j++)
                acc[i][j] = __builtin_amdgcn_mfma_f32_16x16x32_bf16(af[i], bfv[j], acc[i][j], 0, 0, 0);
        __syncthreads();   // drains stage vmcnt + all reads of buf
        buf ^= 1;
    }

#pragma unroll
    for (int j = 0; j < 4; j++) {
        int col = nb + wn + j * 16 + lr;
        float bv = bias[col];
#pragma unroll
        for (int i = 0; i < 4; i++) {
            int row0 = mb + wm + i * 16 + lg * 4;
#pragma unroll
            for (int rg = 0; rg < 4; rg++) {
                float v = (acc[i][j][rg] + bv) * scale;
                if (OUTF32)
                    ((float*)outbase)[(size_t)(row0 + rg) * HSZ + col] = v;
                else
                    ((unsigned short*)outbase)[(size_t)proj * (4096 * 1024) +
                                               (size_t)(row0 + rg) * HSZ + col] = f2bf(v);
            }
        }
    }
}

// ---------------------------------------------------------------------------
// Legacy fp32-A GEMM (fallback path if ws is small).
// ---------------------------------------------------------------------------
template<bool ABF16, bool OUTBF16>
__global__ __launch_bounds__(256) void gemm_bt_kernel(
    const void* __restrict__ Aptr, const unsigned short* __restrict__ Bt,
    const float* __restrict__ bias, float scale, void* __restrict__ outp)
{
    __shared__ __align__(16) unsigned short As[128][40];
    __shared__ __align__(16) unsigned short Bs[128][40];

    int t = threadIdx.x;
    int lane = t & 63, w = t >> 6;
    int lr = lane & 15, lg = lane >> 4;
    int mb = blockIdx.y * 128, nb = blockIdx.x * 128;
    int wm = (w >> 1) * 64, wn = (w & 1) * 64;
    int r = t >> 1, cc = (t & 1) * 16;

    f32x4 acc[4][4] = {};

    for (int kt = 0; kt < HSZ; kt += 32) {
        if (ABF16) {
            const unsigned short* A = (const unsigned short*)Aptr + (size_t)(mb + r) * HSZ + kt + cc;
            *(uint4*)&As[r][cc]     = ((const uint4*)A)[0];
            *(uint4*)&As[r][cc + 8] = ((const uint4*)A)[1];
        } else {
            const float* A = (const float*)Aptr + (size_t)(mb + r) * HSZ + kt + cc;
            unsigned short tmp[16];
#pragma unroll
            for (int q = 0; q < 4; q++) {
                float4 v = ((const float4*)A)[q];
                tmp[q * 4 + 0] = f2bf(v.x); tmp[q * 4 + 1] = f2bf(v.y);
                tmp[q * 4 + 2] = f2bf(v.z); tmp[q * 4 + 3] = f2bf(v.w);
            }
            *(uint4*)&As[r][cc]     = *(uint4*)&tmp[0];
            *(uint4*)&As[r][cc + 8] = *(uint4*)&tmp[8];
        }
        {
            const unsigned short* B = Bt + (size_t)(nb + r) * HSZ + kt + cc;
            *(uint4*)&Bs[r][cc]     = ((const uint4*)B)[0];
            *(uint4*)&Bs[r][cc + 8] = ((const uint4*)B)[1];
        }
        __syncthreads();

        short8v af[4], bf[4];
#pragma unroll
        for (int s = 0; s < 4; s++) af[s] = *(const short8v*)&As[wm + s * 16 + lr][8 * lg];
#pragma unroll
        for (int s = 0; s < 4; s++) bf[s] = *(const short8v*)&Bs[wn + s * 16 + lr][8 * lg];
#pragma unroll
        for (int i = 0; i < 4; i++)
#pragma unroll
            for (int j = 0; j < 4; j++)
                acc[i][j] = __builtin_amdgcn_mfma_f32_16x16x32_bf16(af[i], bf[j], acc[i][j], 0, 0, 0);
        __syncthreads();
    }

#pragma unroll
    for (int j = 0; j < 4; j++) {
        int col = nb + wn + j * 16 + lr;
        float bv = bias[col];
#pragma unroll
        for (int i = 0; i < 4; i++) {
            int row0 = mb + wm + i * 16 + lg * 4;
#pragma unroll
            for (int rg = 0; rg < 4; rg++) {
                float v = (acc[i][j][rg] + bv) * scale;
                if (OUTBF16)
                    ((unsigned short*)outp)[(size_t)(row0 + rg) * HSZ + col] = f2bf(v);
                else
                    ((float*)outp)[(size_t)(row0 + rg) * HSZ + col] = v;
            }
        }
    }
}

// ---------------------------------------------------------------------------
// Phase 1: rcpC[head][j] = 1 / sum_{i>=j} exp(S_ij). S^T = mfma(K,Q).
// XCD remap (4 heads/XCD) + per-CU complementary jb pairing: co-resident
// blocks (raw, raw+256, ...) differ in idx bit5 -> alternate jb direction,
// so each CU's 4 blocks pair (j, 31-j) with constant work sum.
// ---------------------------------------------------------------------------
__global__ __launch_bounds__(256) void colsum_kernel(
    const unsigned short* __restrict__ Qb, const unsigned short* __restrict__ Kb,
    float* __restrict__ rcpC)
{
    int raw = blockIdx.x;
    int xcd = raw & 7, idx = raw >> 3;        // idx in [0,128)
    int head = xcd * 4 + (idx >> 5);          // 4 heads per XCD
    int jbi = idx & 31;
    if ((idx >> 5) & 1) jbi = 31 - jbi;       // complementary per co-resident set
    int jb = jbi * 64;
    const unsigned short* Qh = Qb + (size_t)head * L * HDIM;
    const unsigned short* Kh = Kb + (size_t)head * L * HDIM;
    int t = threadIdx.x, lane = t & 63, w = t >> 6;
    int lr = lane & 15, lg = lane >> 4;

    short8v af[4][2];
#pragma unroll
    for (int sj = 0; sj < 4; sj++)
#pragma unroll
        for (int kk = 0; kk < 2; kk++)
            af[sj][kk] = *(const short8v*)&Kh[(size_t)(jb + sj * 16 + lr) * HDIM + kk * 32 + 8 * lg];

    float accs[4][4] = {};

    int it0 = jb + w * 16;
    short8v bc0 = *(const short8v*)&Qh[(size_t)(it0 + lr) * HDIM + 8 * lg];
    short8v bc1 = *(const short8v*)&Qh[(size_t)(it0 + lr) * HDIM + 32 + 8 * lg];

    for (int it = it0; it < L; it += 64) {
        int itn = (it + 64 < L) ? it + 64 : it;
        short8v bn0 = *(const short8v*)&Qh[(size_t)(itn + lr) * HDIM + 8 * lg];
        short8v bn1 = *(const short8v*)&Qh[(size_t)(itn + lr) * HDIM + 32 + 8 * lg];
        int i = it + lr;
#pragma unroll
        for (int sj = 0; sj < 4; sj++) {
            f32x4 d = {0.0f, 0.0f, 0.0f, 0.0f};
            d = __builtin_amdgcn_mfma_f32_16x16x32_bf16(af[sj][0], bc0, d, 0, 0, 0);
            d = __builtin_amdgcn_mfma_f32_16x16x32_bf16(af[sj][1], bc1, d, 0, 0, 0);
#pragma unroll
            for (int rg = 0; rg < 4; rg++) {
                int j = jb + sj * 16 + lg * 4 + rg;
                if (i >= j) accs[sj][rg] += __expf(d[rg]);
            }
        }
        bc0 = bn0; bc1 = bn1;
    }

    __shared__ float part[4][64];
#pragma unroll
    for (int sj = 0; sj < 4; sj++)
#pragma unroll
        for (int rg = 0; rg < 4; rg++) {
            float v = accs[sj][rg];
            v += __shfl_xor(v, 1); v += __shfl_xor(v, 2);
            v += __shfl_xor(v, 4); v += __shfl_xor(v, 8);
            if (lr == 0) part[w][sj * 16 + lg * 4 + rg] = v;
        }
    __syncthreads();
    if (t < 64) {
        float s = part[0][t] + part[1][t] + part[2][t] + part[3][t];
        rcpC[(size_t)head * L + jb + t] = 1.0f / s;
    }
}

// ---------------------------------------------------------------------------
// V transpose with rcpC folded: Vt[p][c][j] = bf16(V[p][j][c] * rcpC[p][j]).
// ---------------------------------------------------------------------------
__global__ __launch_bounds__(256) void vtrans_kernel(
    const unsigned short* __restrict__ Vb, const float* __restrict__ rcpC,
    unsigned short* __restrict__ Vt)
{
    int p = blockIdx.y;
    int j0 = blockIdx.x * 64;
    const unsigned short* Vp = Vb + (size_t)p * L * HDIM;
    unsigned short* Tp = Vt + (size_t)p * HDIM * L;
    __shared__ __align__(16) unsigned short tl[64][72];
    int t = threadIdx.x;
    int jl = t >> 2, c0 = (t & 3) * 16;
    float rcv = rcpC[(size_t)p * L + j0 + jl];
    const unsigned short* src = Vp + (size_t)(j0 + jl) * HDIM + c0;
    unsigned short raw[16];
    *(uint4*)&raw[0] = ((const uint4*)src)[0];
    *(uint4*)&raw[8] = ((const uint4*)src)[1];
#pragma unroll
    for (int e = 0; e < 16; e++) tl[jl][c0 + e] = f2bf(bf2f(raw[e]) * rcv);
    __syncthreads();
    int cl = t >> 2, jc = (t & 3) * 16;
    unsigned short tmp[16];
#pragma unroll
    for (int e = 0; e < 16; e++) tmp[e] = tl[jc + e][cl];
    unsigned short* dst = Tp + (size_t)cl * L + j0 + jc;
    ((uint4*)dst)[0] = *(uint4*)&tmp[0];
    ((uint4*)dst)[1] = *(uint4*)&tmp[8];
}

// ---------------------------------------------------------------------------
// Phase 2 (LDS-staged flash loop, 8 waves): block covers 128 q-rows.
// Complementary pairing: co-resident blocks (raw, raw+256) differ in idx
// bit5, XORed into snake parity -> each CU gets one big + one small q-tile.
// ---------------------------------------------------------------------------
__global__ __launch_bounds__(512) void attn_kernel(
    const unsigned short* __restrict__ Qb, const unsigned short* __restrict__ Kb,
    const unsigned short* __restrict__ Vtg, unsigned short* __restrict__ Ctx)
{
    int raw = blockIdx.x;
    int xcd = raw & 7, idx = raw >> 3;            // idx in [0,64)
    int head = xcd * 4 + (idx >> 4);              // 4 heads per XCD
    int jpos = (idx & 15) ^ ((idx >> 5) & 1);     // complementary per co-resident pair
    int qtile = (jpos & 1) ? (jpos >> 1) : (15 - (jpos >> 1));   // snake
    int qb = qtile * 128;
    int nt = qb / 64 + 2;                          // KV tiles this block touches

    const unsigned short* Qh = Qb + (size_t)head * L * HDIM;
    const unsigned short* Kh = Kb + (size_t)head * L * HDIM;
    const unsigned short* Vh = Vtg + (size_t)head * HDIM * L;   // [64][2048]
    unsigned short* Ch = Ctx + (size_t)head * L * HDIM;

    int t = threadIdx.x;
    int lane = t & 63, w = t >> 6;
    int ws = w & 3;                                // strip
    int w2 = w >> 2;                               // which 32-j window
    int lr = lane & 15, lg = lane >> 4;
    int iw = qb + ws * 32;
    int src0 = ((lane & 16) << 1) + lr;
    int src1 = src0 + 16;
    bool jlow = (lg < 2);

    // SMEM[0..1] = Kt dbuf, SMEM[2..3] = Vl dbuf; reused as f32x4 dump at end
    __shared__ __align__(16) unsigned short SMEM[4][4096];

    int srow = ws * 8 + (lane >> 3);
    int soff = ((lane & 7) ^ (lane >> 3)) * 8;     // pre-XORed source offset

    auto stageT = [&](int buf, int jt) {
        if (w < 4) {
            gload_lds16(Kh + (size_t)(jt + srow) * HDIM + soff,      &SMEM[buf][ws * 512]);
            gload_lds16(Kh + (size_t)(jt + srow + 32) * HDIM + soff, &SMEM[buf][ws * 512 + 2048]);
        } else {
            gload_lds16(Vh + (size_t)srow * L + jt + soff,           &SMEM[2 + buf][ws * 512]);
            gload_lds16(Vh + (size_t)(srow + 32) * L + jt + soff,    &SMEM[2 + buf][ws * 512 + 2048]);
        }
    };

    short8v bq[2][2];
#pragma unroll
    for (int isub = 0; isub < 2; isub++)
#pragma unroll
        for (int kd = 0; kd < 2; kd++)
            bq[isub][kd] = *(const short8v*)&Qh[(size_t)(iw + isub * 16 + lr) * HDIM + kd * 32 + 8 * lg];

    f32x4 acc[4][2] = {};   // ctx^T [csub][isub]: D(c=lg*4+rg, i=lr)

    stageT(0, 0);
    __syncthreads();

    for (int tt = 0; tt < nt; ++tt) {
        int buf = tt & 1;
        if (tt + 1 < nt) stageT(buf ^ 1, (tt + 1) * 64);

        int jt32 = tt * 64 + w2 * 32;
        if (jt32 <= iw + 31) {
            short8v ak[2][2];
#pragma unroll
            for (int jsub = 0; jsub < 2; jsub++)
#pragma unroll
                for (int kd = 0; kd < 2; kd++) {
                    int lrow = w2 * 32 + jsub * 16 + lr;
                    int off = lrow * 64 + ((((kd << 2) | lg) ^ (lr & 7)) << 3);
                    ak[jsub][kd] = *(const short8v*)&SMEM[buf][off];
                }
            short8v av[4];
#pragma unroll
            for (int csub = 0; csub < 4; csub++) {
                int vrow = csub * 16 + lr;
                int off = vrow * 64 + ((((w2 << 2) | lg) ^ (lr & 7)) << 3);
                av[csub] = *(const short8v*)&SMEM[2 + buf][off];
            }

            unsigned int pk[2][2][2];   // [jsub][isub][word]
#pragma unroll
            for (int jsub = 0; jsub < 2; jsub++)
#pragma unroll
                for (int isub = 0; isub < 2; isub++) {
                    f32x4 s = {0.0f, 0.0f, 0.0f, 0.0f};
                    s = __builtin_amdgcn_mfma_f32_16x16x32_bf16(ak[jsub][0], bq[isub][0], s, 0, 0, 0);
                    s = __builtin_amdgcn_mfma_f32_16x16x32_bf16(ak[jsub][1], bq[isub][1], s, 0, 0, 0);
                    int i = iw + isub * 16 + lr;
                    int jb0 = jt32 + jsub * 16 + lg * 4;
                    float p[4];
#pragma unroll
                    for (int rg = 0; rg < 4; rg++)
                        p[rg] = (jb0 + rg <= i) ? __expf(s[rg]) : 0.0f;
                    pk[jsub][isub][0] = cvt_pk_bf16(p[0], p[1]);
                    pk[jsub][isub][1] = cvt_pk_bf16(p[2], p[3]);
                }
            __builtin_amdgcn_s_setprio(1);
#pragma unroll
            for (int isub = 0; isub < 2; isub++) {
                int a0 = __shfl((int)pk[0][isub][0], src0);
                int a1 = __shfl((int)pk[0][isub][1], src0);
                int a2 = __shfl((int)pk[0][isub][0], src1);
                int a3 = __shfl((int)pk[0][isub][1], src1);
                int b0 = __shfl((int)pk[1][isub][0], src0);
                int b1 = __shfl((int)pk[1][isub][1], src0);
                int b2 = __shfl((int)pk[1][isub][0], src1);
                int b3 = __shfl((int)pk[1][isub][1], src1);
                int4 wvv;
                wvv.x = jlow ? a0 : b0;
                wvv.y = jlow ? a1 : b1;
                wvv.z = jlow ? a2 : b2;
                wvv.w = jlow ? a3 : b3;
                short8v bp = __builtin_bit_cast(short8v, wvv);
#pragma unroll
                for (int csub = 0; csub < 4; csub++)
                    acc[csub][isub] = __builtin_amdgcn_mfma_f32_16x16x32_bf16(av[csub], bp, acc[csub][isub], 0, 0, 0);
            }
            __builtin_amdgcn_s_setprio(0);
        }
        __syncthreads();   // stage(t+1) drained + all reads of buf done
    }

    // cross-wave pair reduction: waves 4-7 dump acc to LDS, waves 0-3 add+store
    uint4* red = (uint4*)SMEM;   // 2048 uint4 = 32 KB
    if (w >= 4) {
#pragma unroll
        for (int csub = 0; csub < 4; csub++)
#pragma unroll
            for (int isub = 0; isub < 2; isub++)
                red[((ws * 8) + csub * 2 + isub) * 64 + lane] =
                    __builtin_bit_cast(uint4, acc[csub][isub]);
    }
    __syncthreads();
    if (w < 4) {
#pragma unroll
        for (int csub = 0; csub < 4; csub++)
#pragma unroll
            for (int isub = 0; isub < 2; isub++)
                acc[csub][isub] += __builtin_bit_cast(f32x4,
                    red[((ws * 8) + csub * 2 + isub) * 64 + lane]);

#pragma unroll
        for (int csub = 0; csub < 4; csub++)
#pragma unroll
            for (int isub = 0; isub < 2; isub++) {
                int i = iw + isub * 16 + lr;
                int c0 = csub * 16 + lg * 4;
                unsigned short t4[4];
#pragma unroll
                for (int rg = 0; rg < 4; rg++) t4[rg] = f2bf(acc[csub][isub][rg]);
                *(uint2*)&Ch[(size_t)i * HDIM + c0] = *(uint2*)t4;
            }
    }
}

// ---------------------------------------------------------------------------
extern "C" void kernel_launch(void* const* d_in, const int* in_sizes, int n_in,
                              void* d_out, int out_size, void* d_ws, size_t ws_size,
                              hipStream_t stream)
{
    const float* H_q = (const float*)d_in[0];
    const float* H_k = (const float*)d_in[1];
    const float* H_v = (const float*)d_in[2];
    const float* W_q = (const float*)d_in[3];
    const float* b_q = (const float*)d_in[4];
    const float* W_k = (const float*)d_in[5];
    const float* b_k = (const float*)d_in[6];
    const float* W_v = (const float*)d_in[7];
    const float* b_v = (const float*)d_in[8];
    const float* W_o = (const float*)d_in[9];
    const float* b_o = (const float*)d_in[10];

    char* ws = (char*)d_ws;
    const size_t MB = (size_t)1 << 20;
    const float scale = 0.03125f;  // 1/sqrt(1024)

    if (ws_size >= 60 * MB) {
        unsigned short* Hbf = (unsigned short*)(ws);
        unsigned short* Vt  = (unsigned short*)(ws);
        unsigned short* Ctx = (unsigned short*)(ws + 8 * MB);
        unsigned short* Wt4 = (unsigned short*)(ws + 24 * MB);
        unsigned short* Qb  = (unsigned short*)(ws + 32 * MB);
        unsigned short* Kb  = (unsigned short*)(ws + 40 * MB);
        unsigned short* Vb  = (unsigned short*)(ws + 48 * MB);
        float* rcpC = (float*)(ws + 56 * MB);

        wtrans_kernel<<<dim3(16, 16, 4), 256, 0, stream>>>(W_q, W_k, W_v, W_o, Wt4);
        hconv_kernel<<<dim3(2048, 3), 256, 0, stream>>>(H_q, H_k, H_v, Hbf);
        gemm_glds_kernel<false><<<dim3(24, 32), 256, 0, stream>>>(
            Hbf, Wt4, b_q, b_k, b_v, scale, 1.0f, Qb);
        colsum_kernel<<<1024, 256, 0, stream>>>(Qb, Kb, rcpC);
        vtrans_kernel<<<dim3(32, 32), 256, 0, stream>>>(Vb, rcpC, Vt);
        attn_kernel<<<512, 512, 0, stream>>>(Qb, Kb, Vt, Ctx);
        gemm_glds_kernel<true><<<dim3(8, 32), 256, 0, stream>>>(
            Ctx, Wt4 + (size_t)3 * 1024 * 1024, b_o, b_o, b_o, 1.0f, 1.0f, d_out);
    } else {
        unsigned short* Qb  = (unsigned short*)(ws + 0 * MB);
        unsigned short* Kb  = (unsigned short*)(ws + 8 * MB);
        unsigned short* Vt  = (unsigned short*)(ws + 16 * MB);
        unsigned short* Vb  = (unsigned short*)(ws + 24 * MB);
        unsigned short* Ctx = (unsigned short*)(ws + 24 * MB);
        unsigned short* Wt4 = (unsigned short*)(ws + 32 * MB);
        float* rcpC = (float*)(ws + 40 * MB);

        wtrans_kernel<<<dim3(16, 16, 4), 256, 0, stream>>>(W_q, W_k, W_v, W_o, Wt4);
        gemm_bt_kernel<false, true><<<dim3(8, 32), 256, 0, stream>>>(H_q, Wt4, b_q, scale, Qb);
        gemm_bt_kernel<false, true><<<dim3(8, 32), 256, 0, stream>>>(H_k, Wt4 + (size_t)1024 * 1024, b_k, scale, Kb);
        gemm_bt_kernel<false, true><<<dim3(8, 32), 256, 0, stream>>>(H_v, Wt4 + (size_t)2 * 1024 * 1024, b_v, 1.0f, Vb);
        colsum_kernel<<<1024, 256, 0, stream>>>(Qb, Kb, rcpC);
        vtrans_kernel<<<dim3(32, 32), 256, 0, stream>>>(Vb, rcpC, Vt);
        attn_kernel<<<512, 512, 0, stream>>>(Qb, Kb, Vt, Ctx);
        gemm_bt_kernel<true, false><<<dim3(8, 32), 256, 0, stream>>>(Ctx, Wt4 + (size_t)3 * 1024 * 1024, b_o, 1.0f, d_out);
    }
}